// Round 5
// baseline (1517.460 us; speedup 1.0000x reference)
//
#include <hip/hip_runtime.h>
#include <math.h>

// ---------------- workspace layout (floats) ----------------
#define WS_W12   0                         // [9*9][32]        = 2592
#define WS_B12   2592                      // 32
#define WS_W34   2624                      // [32*81][64]      = 165888
#define WS_B34   (2624 + 165888)           // 64
#define WS_P1    (WS_B34 + 64)             // [64][30][30][32] = 1843200
#define WS_EMBT  (WS_P1 + 64*30*30*32)     // [1600][64]       = 102400
// overlays (lifetimes disjoint from P1):
#define WS_WPART WS_P1                     // [8][165888] = 1327104 (before conv12)
#define WS_BPART (WS_P1 + 8*165888)        // [8][64]
#define WS_HID   WS_P1                     // [2*256][64] (after conv34)

// ---------------- kernel A1: compose conv1*conv2 -> 9x9, 1->32ch ----------
__global__ __launch_bounds__(128) void k_prep12(
    const float* __restrict__ w1, const float* __restrict__ b1,
    const float* __restrict__ w2, const float* __restrict__ b2,
    float* __restrict__ W12, float* __restrict__ B12)
{
    __shared__ float sW2[800];
    __shared__ float sW1[800];
    int oc = blockIdx.x;
    int t  = threadIdx.x;
    for (int i = t; i < 800; i += 128) {
        sW2[i] = w2[oc * 800 + i];
        sW1[i] = w1[i];
    }
    __syncthreads();
    if (t < 81) {
        int u = t / 9, v = t % 9;
        float acc[4] = {0.f, 0.f, 0.f, 0.f};
        #pragma unroll
        for (int e = 0; e < 25; ++e) {
            int ey = e / 5, ex = e % 5;
            int du = u - ey, dv = v - ex;
            if ((unsigned)du <= 4u && (unsigned)dv <= 4u) {
                int ep = du * 5 + dv;
                for (int mc = 0; mc < 32; ++mc)
                    acc[e & 3] = fmaf(sW2[mc * 25 + e], sW1[mc * 25 + ep],
                                      acc[e & 3]);
            }
        }
        W12[t * 32 + oc] = (acc[0] + acc[1]) + (acc[2] + acc[3]);
    }
    if (t < 32) {
        float ws = 0.f;
        #pragma unroll
        for (int e = 0; e < 25; ++e) ws += sW2[t * 25 + e];
        float p = b1[t] * ws;
        #pragma unroll
        for (int off = 16; off; off >>= 1) p += __shfl_down(p, off, 64);
        if (t == 0) B12[oc] = p + b2[oc];
    }
}

// ---------------- kernel A2a: conv3*conv4 partials (register outer product)
// grid = 64: blockIdx = icg*8 + mcc. block 256: wave = icl (t>>6), lane = oc.
__global__ __launch_bounds__(256) void k_prep34p(
    const float* __restrict__ w3, const float* __restrict__ b3,
    const float* __restrict__ w4,
    float* __restrict__ Wpart, float* __restrict__ Bpart)
{
    __shared__ float sW3c[800];            // [mcl 8][icl 4][e 25]
    int icg = blockIdx.x >> 3;
    int mcc = blockIdx.x & 7;
    int t   = threadIdx.x;
    int oc  = t & 63;
    int icl = t >> 6;                      // wave-uniform
    int ic  = icg * 4 + icl;

    for (int i = t; i < 800; i += 256) {
        int mcl = i / 100, r = i % 100;    // r = icl2*25 + e
        sW3c[i] = w3[(mcc * 8 + mcl) * 800 + icg * 100 + r];
    }
    __syncthreads();

    float acc[81];
    #pragma unroll
    for (int u = 0; u < 81; ++u) acc[u] = 0.f;
    float bacc = 0.f;

    for (int mcl = 0; mcl < 8; ++mcl) {
        int mc = mcc * 8 + mcl;
        float w4r[25];
        #pragma unroll
        for (int e = 0; e < 25; ++e) w4r[e] = w4[oc * 1600 + mc * 25 + e];
        const float* w3r = &sW3c[(mcl * 4 + icl) * 25];
        #pragma unroll
        for (int e2 = 0; e2 < 25; ++e2) {
            int ey = e2 / 5, ex = e2 % 5;
            #pragma unroll
            for (int e1 = 0; e1 < 25; ++e1) {
                int u = (ey + e1 / 5) * 9 + (ex + e1 % 5);   // compile-time
                acc[u] = fmaf(w4r[e2], w3r[e1], acc[u]);
            }
        }
        if (icl == 0) {
            float ws = 0.f;
            #pragma unroll
            for (int e = 0; e < 25; ++e) ws += w4r[e];
            bacc = fmaf(b3[mc], ws, bacc);
        }
    }

    for (int uv = 0; uv < 81; ++uv)
        Wpart[((mcc * 32 + ic) * 81 + uv) * 64 + oc] = acc[uv];
    if (icl == 0) Bpart[mcc * 64 + oc] = bacc;
}

// ---------------- kernel A2b: sum partials ------------------------------
__global__ __launch_bounds__(256) void k_prep34s(
    const float* __restrict__ Wpart, const float* __restrict__ Bpart,
    const float* __restrict__ b4,
    float* __restrict__ W34, float* __restrict__ B34)
{
    int i = blockIdx.x * 256 + threadIdx.x;
    if (i < 165888) {
        float s = 0.f;
        #pragma unroll
        for (int c = 0; c < 8; ++c) s += Wpart[c * 165888 + i];
        W34[i] = s;
    }
    if (blockIdx.x == 648 && threadIdx.x < 64) {
        int oc = threadIdx.x;
        float s = b4[oc];
        #pragma unroll
        for (int c = 0; c < 8; ++c) s += Bpart[c * 64 + oc];
        B34[oc] = s;
    }
}

// ---------------- kernel B: fused 9x9 conv12 + 4x4 maxpool ----------------
__global__ __launch_bounds__(256) void k_conv12(
    const float* __restrict__ x, const float* __restrict__ W12,
    const float* __restrict__ B12, float* __restrict__ P1)
{
    __shared__ float sIn[12][128];

    int b  = blockIdx.x / 30;
    int py = blockIdx.x % 30;
    int t  = threadIdx.x;

    const float* xb = x + b * 128 * 128;
    for (int i = t; i < 12 * 32; i += 256) {
        int row = i >> 5, c4 = i & 31;
        ((float4*)sIn[row])[c4] =
            ((const float4*)(xb + (4 * py + row) * 128))[c4];
    }

    int oc = t & 31;
    int pg = t >> 5;
    float w[81];
    #pragma unroll
    for (int e = 0; e < 81; ++e) w[e] = W12[e * 32 + oc];
    float bias = B12[oc];
    __syncthreads();

    for (int j = 0; j < 4; ++j) {
        int px = pg + 8 * j;
        if (px >= 30) break;
        float acc[4][4];
        #pragma unroll
        for (int iy = 0; iy < 4; ++iy)
            #pragma unroll
            for (int ix = 0; ix < 4; ++ix) acc[iy][ix] = 0.f;

        #pragma unroll
        for (int r = 0; r < 12; ++r) {
            const float* rp = sIn[r] + 4 * px;
            float4 A  = ((const float4*)rp)[0];
            float4 Bq = ((const float4*)rp)[1];
            float4 Cq = ((const float4*)rp)[2];
            float win[12] = {A.x, A.y, A.z, A.w, Bq.x, Bq.y, Bq.z, Bq.w,
                             Cq.x, Cq.y, Cq.z, Cq.w};
            #pragma unroll
            for (int iy = 0; iy < 4; ++iy) {
                int ky = r - iy;
                if (ky < 0 || ky > 8) continue;
                #pragma unroll
                for (int ix = 0; ix < 4; ++ix)
                    #pragma unroll
                    for (int kx = 0; kx < 9; ++kx)
                        acc[iy][ix] = fmaf(w[ky * 9 + kx], win[ix + kx],
                                           acc[iy][ix]);
            }
        }
        float m = -INFINITY;
        #pragma unroll
        for (int iy = 0; iy < 4; ++iy)
            #pragma unroll
            for (int ix = 0; ix < 4; ++ix) m = fmaxf(m, acc[iy][ix]);
        P1[((b * 30 + py) * 30 + px) * 32 + oc] = m + bias;
    }
}

// ---------------- kernel C: fused 9x9 conv34 + 4x4 maxpool ----------------
// grid = 640 (b*5py*2oh); block 320 = 32 ocl * 10 grp.
// sIn: [ic][row][f4slot ^ (ic&7)][4] — XOR swizzle so windows read as b128
// (conflict-free broadcast) while staging writes stay cheap.
__global__ __launch_bounds__(320, 4) void k_conv34(
    const float* __restrict__ P1, const float* __restrict__ W34,
    const float* __restrict__ B34, float* __restrict__ embT)
{
    __shared__ float sIn[32 * 12 * 32];    // 48 KB
    __shared__ float sPool[10][32];

    int bi  = blockIdx.x;
    int b   = bi / 10;
    int rem = bi % 10;
    int py  = rem >> 1;
    int oh  = rem & 1;
    int t   = threadIdx.x;

    for (int i = t; i < 2880; i += 320) {
        int icq = i & 7;
        int rc  = i >> 3;
        int row = rc / 30, col = rc % 30;
        float4 v = ((const float4*)(P1 +
                    ((b * 30 + 4 * py + row) * 30 + col) * 32))[icq];
        int base = row * 32 + (col & 3);
        int c2   = col >> 2;
        int ic0  = icq * 4;
        sIn[(ic0 + 0) * 384 + base + ((c2 ^ ((ic0 + 0) & 7)) << 2)] = v.x;
        sIn[(ic0 + 1) * 384 + base + ((c2 ^ ((ic0 + 1) & 7)) << 2)] = v.y;
        sIn[(ic0 + 2) * 384 + base + ((c2 ^ ((ic0 + 2) & 7)) << 2)] = v.z;
        sIn[(ic0 + 3) * 384 + base + ((c2 ^ ((ic0 + 3) & 7)) << 2)] = v.w;
    }
    __syncthreads();

    int ocl  = t & 31;
    int oc   = ocl + (oh << 5);
    int grp  = t >> 5;
    int iyh  = grp / 5;
    int cgrp = grp % 5;

    float acc[2][4];
    #pragma unroll
    for (int d = 0; d < 2; ++d)
        #pragma unroll
        for (int ix = 0; ix < 4; ++ix) acc[d][ix] = 0.f;

    for (int ic = 0; ic < 32; ++ic) {
        float w[81];
        #pragma unroll
        for (int e = 0; e < 81; ++e)
            w[e] = W34[(ic * 81 + e) * 64 + oc];

        const float* base = sIn + ic * 384;
        int sz = ic & 7;

        #pragma unroll
        for (int ro = 0; ro < 10; ++ro) {
            int r32 = (2 * iyh + ro) * 32;
            float4 A  = *(const float4*)(base + r32 + (((cgrp + 0) ^ sz) << 2));
            float4 Bq = *(const float4*)(base + r32 + (((cgrp + 1) ^ sz) << 2));
            float4 Cq = *(const float4*)(base + r32 + (((cgrp + 2) ^ sz) << 2));
            float win[12] = {A.x, A.y, A.z, A.w, Bq.x, Bq.y, Bq.z, Bq.w,
                             Cq.x, Cq.y, Cq.z, Cq.w};
            #pragma unroll
            for (int d = 0; d < 2; ++d) {
                int ky = ro - d;
                if (ky < 0 || ky > 8) continue;
                #pragma unroll
                for (int ix = 0; ix < 4; ++ix)
                    #pragma unroll
                    for (int kx = 0; kx < 9; ++kx)
                        acc[d][ix] = fmaf(w[ky * 9 + kx], win[ix + kx],
                                          acc[d][ix]);
            }
        }
    }

    float pmax = -INFINITY;
    #pragma unroll
    for (int d = 0; d < 2; ++d)
        #pragma unroll
        for (int ix = 0; ix < 4; ++ix) pmax = fmaxf(pmax, acc[d][ix]);
    sPool[grp][ocl] = pmax;
    __syncthreads();

    if (grp < 5) {
        float m = fmaxf(sPool[grp][ocl], sPool[grp + 5][ocl]) + B34[oc];
        embT[(oc * 25 + py * 5 + grp) * 64 + b] = m;
    }
}

// ---------------- kernel D1: first FC layer, both heads -------------------
__global__ __launch_bounds__(256) void k_fc1(
    const float* __restrict__ embT,
    const float* __restrict__ w_ed1, const float* __restrict__ b_ed1,
    const float* __restrict__ w_ep1, const float* __restrict__ b_ep1,
    float* __restrict__ hid)
{
    int head = blockIdx.x >> 6;
    int jg   = blockIdx.x & 63;
    int b    = threadIdx.x & 63;
    int jl   = __builtin_amdgcn_readfirstlane(threadIdx.x >> 6);
    int j    = jg * 4 + jl;

    const float* W1 = head ? w_ep1 : w_ed1;
    float s = head ? b_ep1[j] : b_ed1[j];
    #pragma unroll 8
    for (int k = 0; k < 1600; ++k)
        s = fmaf(embT[k * 64 + b], W1[k * 256 + j], s);
    hid[(head * 256 + j) * 64 + b] = fmaxf(s, 0.f);
}

// ---------------- kernel D2: second FC layer (3 cols) + sigmoid product ---
__global__ __launch_bounds__(256) void k_fc2(
    const float* __restrict__ hid,
    const float* __restrict__ w_ed2, const float* __restrict__ b_ed2,
    const float* __restrict__ w_ep2, const float* __restrict__ b_ep2,
    const int* __restrict__ esrc, const int* __restrict__ edst,
    float* __restrict__ out)
{
    __shared__ float sl[192];
    int t = threadIdx.x;
    if (t < 192) {
        int q = __builtin_amdgcn_readfirstlane(t >> 6);
        int b = t & 63;
        int c0 = esrc[0], c1 = edst[0];
        int head = (q > 0) ? 1 : 0;
        float acc = 0.f;
        #pragma unroll 4
        for (int j = 0; j < 256; ++j) {
            float w = (q == 0) ? w_ed2[j * 120]
                    : (q == 1) ? w_ep2[j * 36 + c0]
                               : w_ep2[j * 36 + c1];
            acc = fmaf(hid[(head * 256 + j) * 64 + b], w, acc);
        }
        float bias = (q == 0) ? b_ed2[0] : (q == 1) ? b_ep2[c0] : b_ep2[c1];
        sl[q * 64 + b] = 1.f / (1.f + expf(-(acc + bias)));
    }
    __syncthreads();
    if (t < 64) out[t] = sl[t] * sl[64 + t] * sl[128 + t];
}

// ---------------- launch --------------------------------------------------
extern "C" void kernel_launch(void* const* d_in, const int* in_sizes, int n_in,
                              void* d_out, int out_size, void* d_ws, size_t ws_size,
                              hipStream_t stream)
{
    const float* x     = (const float*)d_in[0];
    const float* w1    = (const float*)d_in[1];
    const float* b1    = (const float*)d_in[2];
    const float* w2    = (const float*)d_in[3];
    const float* b2    = (const float*)d_in[4];
    const float* w3    = (const float*)d_in[5];
    const float* b3    = (const float*)d_in[6];
    const float* w4    = (const float*)d_in[7];
    const float* b4    = (const float*)d_in[8];
    const float* w_ed1 = (const float*)d_in[9];
    const float* b_ed1 = (const float*)d_in[10];
    const float* w_ed2 = (const float*)d_in[11];
    const float* b_ed2 = (const float*)d_in[12];
    const float* w_ep1 = (const float*)d_in[13];
    const float* b_ep1 = (const float*)d_in[14];
    const float* w_ep2 = (const float*)d_in[15];
    const float* b_ep2 = (const float*)d_in[16];
    const int*   esrc  = (const int*)d_in[17];
    const int*   edst  = (const int*)d_in[18];

    float* ws  = (float*)d_ws;
    float* out = (float*)d_out;

    k_prep12<<<32, 128, 0, stream>>>(w1, b1, w2, b2, ws + WS_W12, ws + WS_B12);
    k_prep34p<<<64, 256, 0, stream>>>(w3, b3, w4, ws + WS_WPART, ws + WS_BPART);
    k_prep34s<<<649, 256, 0, stream>>>(ws + WS_WPART, ws + WS_BPART, b4,
                                       ws + WS_W34, ws + WS_B34);
    k_conv12<<<64 * 30, 256, 0, stream>>>(x, ws + WS_W12, ws + WS_B12, ws + WS_P1);
    k_conv34<<<640, 320, 0, stream>>>(ws + WS_P1, ws + WS_W34, ws + WS_B34,
                                      ws + WS_EMBT);
    k_fc1<<<128, 256, 0, stream>>>(ws + WS_EMBT, w_ed1, b_ed1, w_ep1, b_ep1,
                                   ws + WS_HID);
    k_fc2<<<1, 256, 0, stream>>>(ws + WS_HID, w_ed2, b_ed2, w_ep2, b_ep2,
                                 esrc, edst, out);
}

// Round 6
// 424.634 us; speedup vs baseline: 3.5736x; 3.5736x over previous
//
#include <hip/hip_runtime.h>
#include <math.h>

// ---------------- workspace layout (floats) ----------------
#define WS_W12   0                         // [9*9][32]        = 2592
#define WS_B12   2592                      // 32
#define WS_W34   2624                      // [32*81][64]      = 165888
#define WS_B34   (2624 + 165888)           // 64
#define WS_P1    (WS_B34 + 64)             // [64][30][30][32] = 1843200
#define WS_EMBT  (WS_P1 + 64*30*30*32)     // [1600][64]       = 102400
// overlays (lifetimes disjoint from P1):
#define WS_WPART WS_P1                     // [8][165888] (before conv12)
#define WS_BPART (WS_P1 + 8*165888)        // [8][64]
#define WS_HID   WS_P1                     // [2*256][64] (after conv34)

// ---------------- kernel A1: compose conv1*conv2 -> 9x9, 1->32ch ----------
__global__ __launch_bounds__(128) void k_prep12(
    const float* __restrict__ w1, const float* __restrict__ b1,
    const float* __restrict__ w2, const float* __restrict__ b2,
    float* __restrict__ W12, float* __restrict__ B12)
{
    __shared__ float sW2[800];
    __shared__ float sW1[800];
    int oc = blockIdx.x;
    int t  = threadIdx.x;
    for (int i = t; i < 800; i += 128) {
        sW2[i] = w2[oc * 800 + i];
        sW1[i] = w1[i];
    }
    __syncthreads();
    if (t < 81) {
        int u = t / 9, v = t % 9;
        float acc[4] = {0.f, 0.f, 0.f, 0.f};
        #pragma unroll
        for (int e = 0; e < 25; ++e) {
            int ey = e / 5, ex = e % 5;
            int du = u - ey, dv = v - ex;
            if ((unsigned)du <= 4u && (unsigned)dv <= 4u) {
                int ep = du * 5 + dv;
                for (int mc = 0; mc < 32; ++mc)
                    acc[e & 3] = fmaf(sW2[mc * 25 + e], sW1[mc * 25 + ep],
                                      acc[e & 3]);
            }
        }
        W12[t * 32 + oc] = (acc[0] + acc[1]) + (acc[2] + acc[3]);
    }
    if (t < 32) {
        float ws = 0.f;
        #pragma unroll
        for (int e = 0; e < 25; ++e) ws += sW2[t * 25 + e];
        float p = b1[t] * ws;
        #pragma unroll
        for (int off = 16; off; off >>= 1) p += __shfl_down(p, off, 64);
        if (t == 0) B12[oc] = p + b2[oc];
    }
}

// ---------------- kernel A2a: conv3*conv4 partials (register outer product)
__global__ __launch_bounds__(256) void k_prep34p(
    const float* __restrict__ w3, const float* __restrict__ b3,
    const float* __restrict__ w4,
    float* __restrict__ Wpart, float* __restrict__ Bpart)
{
    __shared__ float sW3c[800];            // [mcl 8][icl 4][e 25]
    int icg = blockIdx.x >> 3;
    int mcc = blockIdx.x & 7;
    int t   = threadIdx.x;
    int oc  = t & 63;
    int icl = t >> 6;                      // wave-uniform
    int ic  = icg * 4 + icl;

    for (int i = t; i < 800; i += 256) {
        int mcl = i / 100, r = i % 100;
        sW3c[i] = w3[(mcc * 8 + mcl) * 800 + icg * 100 + r];
    }
    __syncthreads();

    float acc[81];
    #pragma unroll
    for (int u = 0; u < 81; ++u) acc[u] = 0.f;
    float bacc = 0.f;

    for (int mcl = 0; mcl < 8; ++mcl) {
        int mc = mcc * 8 + mcl;
        float w4r[25];
        #pragma unroll
        for (int e = 0; e < 25; ++e) w4r[e] = w4[oc * 1600 + mc * 25 + e];
        const float* w3r = &sW3c[(mcl * 4 + icl) * 25];
        #pragma unroll
        for (int e2 = 0; e2 < 25; ++e2) {
            int ey = e2 / 5, ex = e2 % 5;
            #pragma unroll
            for (int e1 = 0; e1 < 25; ++e1) {
                int u = (ey + e1 / 5) * 9 + (ex + e1 % 5);   // compile-time
                acc[u] = fmaf(w4r[e2], w3r[e1], acc[u]);
            }
        }
        if (icl == 0) {
            float ws = 0.f;
            #pragma unroll
            for (int e = 0; e < 25; ++e) ws += w4r[e];
            bacc = fmaf(b3[mc], ws, bacc);
        }
    }

    for (int uv = 0; uv < 81; ++uv)
        Wpart[((mcc * 32 + ic) * 81 + uv) * 64 + oc] = acc[uv];
    if (icl == 0) Bpart[mcc * 64 + oc] = bacc;
}

// ---------------- kernel A2b: sum partials ------------------------------
__global__ __launch_bounds__(256) void k_prep34s(
    const float* __restrict__ Wpart, const float* __restrict__ Bpart,
    const float* __restrict__ b4,
    float* __restrict__ W34, float* __restrict__ B34)
{
    int i = blockIdx.x * 256 + threadIdx.x;
    if (i < 165888) {
        float s = 0.f;
        #pragma unroll
        for (int c = 0; c < 8; ++c) s += Wpart[c * 165888 + i];
        W34[i] = s;
    }
    if (blockIdx.x == 648 && threadIdx.x < 64) {
        int oc = threadIdx.x;
        float s = b4[oc];
        #pragma unroll
        for (int c = 0; c < 8; ++c) s += Bpart[c * 64 + oc];
        B34[oc] = s;
    }
}

// ---------------- kernel B: fused 9x9 conv12 + 4x4 maxpool ----------------
__global__ __launch_bounds__(256) void k_conv12(
    const float* __restrict__ x, const float* __restrict__ W12,
    const float* __restrict__ B12, float* __restrict__ P1)
{
    __shared__ float sIn[12][128];

    int b  = blockIdx.x / 30;
    int py = blockIdx.x % 30;
    int t  = threadIdx.x;

    const float* xb = x + b * 128 * 128;
    for (int i = t; i < 12 * 32; i += 256) {
        int row = i >> 5, c4 = i & 31;
        ((float4*)sIn[row])[c4] =
            ((const float4*)(xb + (4 * py + row) * 128))[c4];
    }

    int oc = t & 31;
    int pg = t >> 5;
    float w[81];
    #pragma unroll
    for (int e = 0; e < 81; ++e) w[e] = W12[e * 32 + oc];
    float bias = B12[oc];
    __syncthreads();

    for (int j = 0; j < 4; ++j) {
        int px = pg + 8 * j;
        if (px >= 30) break;
        float acc[4][4];
        #pragma unroll
        for (int iy = 0; iy < 4; ++iy)
            #pragma unroll
            for (int ix = 0; ix < 4; ++ix) acc[iy][ix] = 0.f;

        #pragma unroll
        for (int r = 0; r < 12; ++r) {
            const float* rp = sIn[r] + 4 * px;
            float4 A  = ((const float4*)rp)[0];
            float4 Bq = ((const float4*)rp)[1];
            float4 Cq = ((const float4*)rp)[2];
            float win[12] = {A.x, A.y, A.z, A.w, Bq.x, Bq.y, Bq.z, Bq.w,
                             Cq.x, Cq.y, Cq.z, Cq.w};
            #pragma unroll
            for (int iy = 0; iy < 4; ++iy) {
                int ky = r - iy;
                if (ky < 0 || ky > 8) continue;
                #pragma unroll
                for (int ix = 0; ix < 4; ++ix)
                    #pragma unroll
                    for (int kx = 0; kx < 9; ++kx)
                        acc[iy][ix] = fmaf(w[ky * 9 + kx], win[ix + kx],
                                           acc[iy][ix]);
            }
        }
        float m = -INFINITY;
        #pragma unroll
        for (int iy = 0; iy < 4; ++iy)
            #pragma unroll
            for (int ix = 0; ix < 4; ++ix) m = fmaxf(m, acc[iy][ix]);
        P1[((b * 30 + py) * 30 + px) * 32 + oc] = m + bias;
    }
}

// ---------------- kernel C: fused 9x9 conv34 + 4x4 maxpool ----------------
// grid = 64 b * 5 py = 320; block = 640: lane = oc (64), wave = grp (10).
// Weight reads: 256B coalesced per wave (sliding 2x9-row register window,
// no large per-thread array -> no spill). Window reads: wave-uniform
// ds_read_b128 broadcasts, conflict-free.
__global__ __launch_bounds__(640) void k_conv34(
    const float* __restrict__ P1, const float* __restrict__ W34,
    const float* __restrict__ B34, float* __restrict__ embT)
{
    __shared__ float sIn[32 * 384];     // [ic][row12][col30 pad32] = 48 KB
    __shared__ float sPool[10][64];

    int b  = blockIdx.x / 5;
    int py = blockIdx.x % 5;
    int t  = threadIdx.x;

    for (int i = t; i < 2880; i += 640) {
        int icq = i & 7;
        int rc  = i >> 3;                 // 0..359
        int row = rc / 30, col = rc % 30;
        float4 v = ((const float4*)(P1 +
                    ((b * 30 + 4 * py + row) * 30 + col) * 32))[icq];
        int base = row * 32 + col;
        sIn[(icq * 4 + 0) * 384 + base] = v.x;
        sIn[(icq * 4 + 1) * 384 + base] = v.y;
        sIn[(icq * 4 + 2) * 384 + base] = v.z;
        sIn[(icq * 4 + 3) * 384 + base] = v.w;
    }
    __syncthreads();

    int oc   = t & 63;                    // lane
    int grp  = t >> 6;                    // 0..9, wave-uniform
    int iyh  = grp / 5;
    int cgrp = grp % 5;

    float acc[2][4];
    #pragma unroll
    for (int d = 0; d < 2; ++d)
        #pragma unroll
        for (int ix = 0; ix < 4; ++ix) acc[d][ix] = 0.f;

    const float* Wb = W34 + oc;

    for (int ic = 0; ic < 32; ++ic) {
        const float* slab = sIn + ic * 384;
        float wrow[2][9];
        #pragma unroll
        for (int ro = 0; ro < 10; ++ro) {
            if (ro <= 8) {
                #pragma unroll
                for (int kx = 0; kx < 9; ++kx)
                    wrow[ro & 1][kx] = Wb[(ic * 81 + ro * 9 + kx) * 64];
            }
            const float* rp = slab + (2 * iyh + ro) * 32 + 4 * cgrp;
            float4 A  = ((const float4*)rp)[0];
            float4 Bq = ((const float4*)rp)[1];
            float4 Cq = ((const float4*)rp)[2];
            float win[12] = {A.x, A.y, A.z, A.w, Bq.x, Bq.y, Bq.z, Bq.w,
                             Cq.x, Cq.y, Cq.z, Cq.w};
            #pragma unroll
            for (int d = 0; d < 2; ++d) {
                int ky = ro - d;                 // compile-time after unroll
                if (ky < 0 || ky > 8) continue;
                const float* wk = wrow[ky & 1];  // static parity index
                #pragma unroll
                for (int ix = 0; ix < 4; ++ix)
                    #pragma unroll
                    for (int kx = 0; kx < 9; ++kx)
                        acc[d][ix] = fmaf(wk[kx], win[ix + kx], acc[d][ix]);
            }
        }
    }

    float pmax = -INFINITY;
    #pragma unroll
    for (int d = 0; d < 2; ++d)
        #pragma unroll
        for (int ix = 0; ix < 4; ++ix) pmax = fmaxf(pmax, acc[d][ix]);
    sPool[grp][oc] = pmax;
    __syncthreads();

    if (grp < 5) {
        float m = fmaxf(sPool[grp][oc], sPool[grp + 5][oc]) + B34[oc];
        embT[(oc * 25 + py * 5 + grp) * 64 + b] = m;
    }
}

// ---------------- kernel D1: first FC layer, both heads -------------------
__global__ __launch_bounds__(256) void k_fc1(
    const float* __restrict__ embT,
    const float* __restrict__ w_ed1, const float* __restrict__ b_ed1,
    const float* __restrict__ w_ep1, const float* __restrict__ b_ep1,
    float* __restrict__ hid)
{
    int head = blockIdx.x >> 6;
    int jg   = blockIdx.x & 63;
    int b    = threadIdx.x & 63;
    int jl   = __builtin_amdgcn_readfirstlane(threadIdx.x >> 6);
    int j    = jg * 4 + jl;

    const float* W1 = head ? w_ep1 : w_ed1;
    float s = head ? b_ep1[j] : b_ed1[j];
    #pragma unroll 8
    for (int k = 0; k < 1600; ++k)
        s = fmaf(embT[k * 64 + b], W1[k * 256 + j], s);
    hid[(head * 256 + j) * 64 + b] = fmaxf(s, 0.f);
}

// ---------------- kernel D2: second FC layer (3 cols) + sigmoid product ---
__global__ __launch_bounds__(256) void k_fc2(
    const float* __restrict__ hid,
    const float* __restrict__ w_ed2, const float* __restrict__ b_ed2,
    const float* __restrict__ w_ep2, const float* __restrict__ b_ep2,
    const int* __restrict__ esrc, const int* __restrict__ edst,
    float* __restrict__ out)
{
    __shared__ float sl[192];
    int t = threadIdx.x;
    if (t < 192) {
        int q = __builtin_amdgcn_readfirstlane(t >> 6);
        int b = t & 63;
        int c0 = esrc[0], c1 = edst[0];
        int head = (q > 0) ? 1 : 0;
        float acc = 0.f;
        #pragma unroll 4
        for (int j = 0; j < 256; ++j) {
            float w = (q == 0) ? w_ed2[j * 120]
                    : (q == 1) ? w_ep2[j * 36 + c0]
                               : w_ep2[j * 36 + c1];
            acc = fmaf(hid[(head * 256 + j) * 64 + b], w, acc);
        }
        float bias = (q == 0) ? b_ed2[0] : (q == 1) ? b_ep2[c0] : b_ep2[c1];
        sl[q * 64 + b] = 1.f / (1.f + expf(-(acc + bias)));
    }
    __syncthreads();
    if (t < 64) out[t] = sl[t] * sl[64 + t] * sl[128 + t];
}

// ---------------- launch --------------------------------------------------
extern "C" void kernel_launch(void* const* d_in, const int* in_sizes, int n_in,
                              void* d_out, int out_size, void* d_ws, size_t ws_size,
                              hipStream_t stream)
{
    const float* x     = (const float*)d_in[0];
    const float* w1    = (const float*)d_in[1];
    const float* b1    = (const float*)d_in[2];
    const float* w2    = (const float*)d_in[3];
    const float* b2    = (const float*)d_in[4];
    const float* w3    = (const float*)d_in[5];
    const float* b3    = (const float*)d_in[6];
    const float* w4    = (const float*)d_in[7];
    const float* b4    = (const float*)d_in[8];
    const float* w_ed1 = (const float*)d_in[9];
    const float* b_ed1 = (const float*)d_in[10];
    const float* w_ed2 = (const float*)d_in[11];
    const float* b_ed2 = (const float*)d_in[12];
    const float* w_ep1 = (const float*)d_in[13];
    const float* b_ep1 = (const float*)d_in[14];
    const float* w_ep2 = (const float*)d_in[15];
    const float* b_ep2 = (const float*)d_in[16];
    const int*   esrc  = (const int*)d_in[17];
    const int*   edst  = (const int*)d_in[18];

    float* ws  = (float*)d_ws;
    float* out = (float*)d_out;

    k_prep12<<<32, 128, 0, stream>>>(w1, b1, w2, b2, ws + WS_W12, ws + WS_B12);
    k_prep34p<<<64, 256, 0, stream>>>(w3, b3, w4, ws + WS_WPART, ws + WS_BPART);
    k_prep34s<<<649, 256, 0, stream>>>(ws + WS_WPART, ws + WS_BPART, b4,
                                       ws + WS_W34, ws + WS_B34);
    k_conv12<<<64 * 30, 256, 0, stream>>>(x, ws + WS_W12, ws + WS_B12, ws + WS_P1);
    k_conv34<<<320, 640, 0, stream>>>(ws + WS_P1, ws + WS_W34, ws + WS_B34,
                                      ws + WS_EMBT);
    k_fc1<<<128, 256, 0, stream>>>(ws + WS_EMBT, w_ed1, b_ed1, w_ep1, b_ep1,
                                   ws + WS_HID);
    k_fc2<<<1, 256, 0, stream>>>(ws + WS_HID, w_ed2, b_ed2, w_ep2, b_ep2,
                                 esrc, edst, out);
}

// Round 7
// 362.083 us; speedup vs baseline: 4.1909x; 1.1728x over previous
//
#include <hip/hip_runtime.h>
#include <math.h>

// ---------------- workspace layout (floats) ----------------
#define WS_W12   0                         // [9*9][32]        = 2592
#define WS_B12   2592                      // 32
#define WS_W34   2624                      // [32*81][64]      = 165888
#define WS_B34   (2624 + 165888)           // 64
#define WS_P1    (WS_B34 + 64)             // [2][64][30][30][16] = 1843200
#define WS_EMBT  (WS_P1 + 64*30*30*32)     // [1600][64]       = 102400
// overlays (lifetimes disjoint from P1):
#define WS_WPART WS_P1                     // [8][165888] (before conv12)
#define WS_BPART (WS_P1 + 8*165888)        // [8][64]
#define WS_HID   WS_P1                     // [2*256][64] (after conv34)

// ---------------- kernel A1: compose conv1*conv2 -> 9x9, 1->32ch ----------
__global__ __launch_bounds__(128) void k_prep12(
    const float* __restrict__ w1, const float* __restrict__ b1,
    const float* __restrict__ w2, const float* __restrict__ b2,
    float* __restrict__ W12, float* __restrict__ B12)
{
    __shared__ float sW2[800];
    __shared__ float sW1[800];
    int oc = blockIdx.x;
    int t  = threadIdx.x;
    for (int i = t; i < 800; i += 128) {
        sW2[i] = w2[oc * 800 + i];
        sW1[i] = w1[i];
    }
    __syncthreads();
    if (t < 81) {
        int u = t / 9, v = t % 9;
        float acc[4] = {0.f, 0.f, 0.f, 0.f};
        #pragma unroll
        for (int e = 0; e < 25; ++e) {
            int ey = e / 5, ex = e % 5;
            int du = u - ey, dv = v - ex;
            if ((unsigned)du <= 4u && (unsigned)dv <= 4u) {
                int ep = du * 5 + dv;
                for (int mc = 0; mc < 32; ++mc)
                    acc[e & 3] = fmaf(sW2[mc * 25 + e], sW1[mc * 25 + ep],
                                      acc[e & 3]);
            }
        }
        W12[t * 32 + oc] = (acc[0] + acc[1]) + (acc[2] + acc[3]);
    }
    if (t < 32) {
        float ws = 0.f;
        #pragma unroll
        for (int e = 0; e < 25; ++e) ws += sW2[t * 25 + e];
        float p = b1[t] * ws;
        #pragma unroll
        for (int off = 16; off; off >>= 1) p += __shfl_down(p, off, 64);
        if (t == 0) B12[oc] = p + b2[oc];
    }
}

// ---------------- kernel A2a: conv3*conv4 partials (register outer product)
__global__ __launch_bounds__(256) void k_prep34p(
    const float* __restrict__ w3, const float* __restrict__ b3,
    const float* __restrict__ w4,
    float* __restrict__ Wpart, float* __restrict__ Bpart)
{
    __shared__ float sW3c[800];            // [mcl 8][icl 4][e 25]
    int icg = blockIdx.x >> 3;
    int mcc = blockIdx.x & 7;
    int t   = threadIdx.x;
    int oc  = t & 63;
    int icl = t >> 6;                      // wave-uniform
    int ic  = icg * 4 + icl;

    for (int i = t; i < 800; i += 256) {
        int mcl = i / 100, r = i % 100;
        sW3c[i] = w3[(mcc * 8 + mcl) * 800 + icg * 100 + r];
    }
    __syncthreads();

    float acc[81];
    #pragma unroll
    for (int u = 0; u < 81; ++u) acc[u] = 0.f;
    float bacc = 0.f;

    for (int mcl = 0; mcl < 8; ++mcl) {
        int mc = mcc * 8 + mcl;
        float w4r[25];
        #pragma unroll
        for (int e = 0; e < 25; ++e) w4r[e] = w4[oc * 1600 + mc * 25 + e];
        const float* w3r = &sW3c[(mcl * 4 + icl) * 25];
        #pragma unroll
        for (int e2 = 0; e2 < 25; ++e2) {
            int ey = e2 / 5, ex = e2 % 5;
            #pragma unroll
            for (int e1 = 0; e1 < 25; ++e1) {
                int u = (ey + e1 / 5) * 9 + (ex + e1 % 5);   // compile-time
                acc[u] = fmaf(w4r[e2], w3r[e1], acc[u]);
            }
        }
        if (icl == 0) {
            float ws = 0.f;
            #pragma unroll
            for (int e = 0; e < 25; ++e) ws += w4r[e];
            bacc = fmaf(b3[mc], ws, bacc);
        }
    }

    for (int uv = 0; uv < 81; ++uv)
        Wpart[((mcc * 32 + ic) * 81 + uv) * 64 + oc] = acc[uv];
    if (icl == 0) Bpart[mcc * 64 + oc] = bacc;
}

// ---------------- kernel A2b: sum partials ------------------------------
__global__ __launch_bounds__(256) void k_prep34s(
    const float* __restrict__ Wpart, const float* __restrict__ Bpart,
    const float* __restrict__ b4,
    float* __restrict__ W34, float* __restrict__ B34)
{
    int i = blockIdx.x * 256 + threadIdx.x;
    if (i < 165888) {
        float s = 0.f;
        #pragma unroll
        for (int c = 0; c < 8; ++c) s += Wpart[c * 165888 + i];
        W34[i] = s;
    }
    if (blockIdx.x == 648 && threadIdx.x < 64) {
        int oc = threadIdx.x;
        float s = b4[oc];
        #pragma unroll
        for (int c = 0; c < 8; ++c) s += Bpart[c * 64 + oc];
        B34[oc] = s;
    }
}

// ---------------- kernel B: fused 9x9 conv12 + 4x4 maxpool ----------------
// P1 layout: [ph=oc>>4][b][row][col][icl=oc&15]
__global__ __launch_bounds__(256) void k_conv12(
    const float* __restrict__ x, const float* __restrict__ W12,
    const float* __restrict__ B12, float* __restrict__ P1)
{
    __shared__ float sIn[12][128];

    int b  = blockIdx.x / 30;
    int py = blockIdx.x % 30;
    int t  = threadIdx.x;

    const float* xb = x + b * 128 * 128;
    for (int i = t; i < 12 * 32; i += 256) {
        int row = i >> 5, c4 = i & 31;
        ((float4*)sIn[row])[c4] =
            ((const float4*)(xb + (4 * py + row) * 128))[c4];
    }

    int oc = t & 31;
    int pg = t >> 5;
    float w[81];
    #pragma unroll
    for (int e = 0; e < 81; ++e) w[e] = W12[e * 32 + oc];
    float bias = B12[oc];
    __syncthreads();

    int ph  = oc >> 4;
    int icl = oc & 15;

    for (int j = 0; j < 4; ++j) {
        int px = pg + 8 * j;
        if (px >= 30) break;
        float acc[4][4];
        #pragma unroll
        for (int iy = 0; iy < 4; ++iy)
            #pragma unroll
            for (int ix = 0; ix < 4; ++ix) acc[iy][ix] = 0.f;

        #pragma unroll
        for (int r = 0; r < 12; ++r) {
            const float* rp = sIn[r] + 4 * px;
            float4 A  = ((const float4*)rp)[0];
            float4 Bq = ((const float4*)rp)[1];
            float4 Cq = ((const float4*)rp)[2];
            float win[12] = {A.x, A.y, A.z, A.w, Bq.x, Bq.y, Bq.z, Bq.w,
                             Cq.x, Cq.y, Cq.z, Cq.w};
            #pragma unroll
            for (int iy = 0; iy < 4; ++iy) {
                int ky = r - iy;
                if (ky < 0 || ky > 8) continue;
                #pragma unroll
                for (int ix = 0; ix < 4; ++ix)
                    #pragma unroll
                    for (int kx = 0; kx < 9; ++kx)
                        acc[iy][ix] = fmaf(w[ky * 9 + kx], win[ix + kx],
                                           acc[iy][ix]);
            }
        }
        float m = -INFINITY;
        #pragma unroll
        for (int iy = 0; iy < 4; ++iy)
            #pragma unroll
            for (int ix = 0; ix < 4; ++ix) m = fmaxf(m, acc[iy][ix]);
        P1[((((ph * 64 + b) * 30 + py) * 30 + px) * 16) + icl] = m + bias;
    }
}

// ---------------- kernel C: fused 9x9 conv34 + 4x4 maxpool ----------------
// grid = (b,py,oh) = 640; block = 320 = 32 ocl * 10 grp.
// ic staged in TWO 16-ic phases into one 24.6KB buffer -> 6 blocks/CU,
// 30 waves/CU resident, whole grid co-resident in one round.
__global__ __launch_bounds__(320) void k_conv34(
    const float* __restrict__ P1, const float* __restrict__ W34,
    const float* __restrict__ B34, float* __restrict__ embT)
{
    __shared__ float sIn[16 * 384];     // [icl][row12][col pad32] = 24.6 KB
    __shared__ float sPool[10][32];

    int bi = blockIdx.x;
    int oh = bi & 1;
    int bp = bi >> 1;
    int b  = bp / 5;
    int py = bp % 5;
    int t  = threadIdx.x;

    int ocl  = t & 31;
    int oc   = ocl + (oh << 5);
    int grp  = t >> 5;            // 0..9
    int iyh  = grp / 5;
    int cgrp = grp % 5;

    float acc[2][4];
    #pragma unroll
    for (int d = 0; d < 2; ++d)
        #pragma unroll
        for (int ix = 0; ix < 4; ++ix) acc[d][ix] = 0.f;

    for (int ph = 0; ph < 2; ++ph) {
        __syncthreads();
        // stage 16 ic: contiguous 1440-float4 span [12 rows][30 col][16 icl]
        const float4* src = (const float4*)(P1 +
            (((ph * 64 + b) * 30 + 4 * py) * 30) * 16);
        for (int i = t; i < 1440; i += 320) {
            float4 v = src[i];
            int icq = i & 3;
            int rc  = i >> 2;                 // row*30+col
            int row = rc / 30, col = rc % 30;
            int base = row * 32 + col;
            sIn[(icq * 4 + 0) * 384 + base] = v.x;
            sIn[(icq * 4 + 1) * 384 + base] = v.y;
            sIn[(icq * 4 + 2) * 384 + base] = v.z;
            sIn[(icq * 4 + 3) * 384 + base] = v.w;
        }
        __syncthreads();

        for (int icl = 0; icl < 16; ++icl) {
            int ic = ph * 16 + icl;
            const float* slab = sIn + icl * 384;
            const float* Wb   = W34 + ic * 81 * 64 + oc;
            float wrow[2][9];
            #pragma unroll
            for (int ro = 0; ro < 10; ++ro) {
                if (ro <= 8) {
                    #pragma unroll
                    for (int kx = 0; kx < 9; ++kx)
                        wrow[ro & 1][kx] = Wb[(ro * 9 + kx) * 64];
                }
                const float* rp = slab + (2 * iyh + ro) * 32 + 4 * cgrp;
                float4 A  = ((const float4*)rp)[0];
                float4 Bq = ((const float4*)rp)[1];
                float4 Cq = ((const float4*)rp)[2];
                float win[12] = {A.x, A.y, A.z, A.w, Bq.x, Bq.y, Bq.z, Bq.w,
                                 Cq.x, Cq.y, Cq.z, Cq.w};
                #pragma unroll
                for (int d = 0; d < 2; ++d) {
                    int ky = ro - d;                 // compile-time
                    if (ky < 0 || ky > 8) continue;
                    const float* wk = wrow[ky & 1];  // static parity index
                    #pragma unroll
                    for (int ix = 0; ix < 4; ++ix)
                        #pragma unroll
                        for (int kx = 0; kx < 9; ++kx)
                            acc[d][ix] = fmaf(wk[kx], win[ix + kx],
                                              acc[d][ix]);
                }
            }
        }
    }

    float pmax = -INFINITY;
    #pragma unroll
    for (int d = 0; d < 2; ++d)
        #pragma unroll
        for (int ix = 0; ix < 4; ++ix) pmax = fmaxf(pmax, acc[d][ix]);
    sPool[grp][ocl] = pmax;
    __syncthreads();

    if (grp < 5) {
        float m = fmaxf(sPool[grp][ocl], sPool[grp + 5][ocl]) + B34[oc];
        embT[(oc * 25 + py * 5 + grp) * 64 + b] = m;
    }
}

// ---------------- kernel D1: first FC layer, both heads -------------------
__global__ __launch_bounds__(256) void k_fc1(
    const float* __restrict__ embT,
    const float* __restrict__ w_ed1, const float* __restrict__ b_ed1,
    const float* __restrict__ w_ep1, const float* __restrict__ b_ep1,
    float* __restrict__ hid)
{
    int head = blockIdx.x >> 6;
    int jg   = blockIdx.x & 63;
    int b    = threadIdx.x & 63;
    int jl   = __builtin_amdgcn_readfirstlane(threadIdx.x >> 6);
    int j    = jg * 4 + jl;

    const float* W1 = head ? w_ep1 : w_ed1;
    float s = head ? b_ep1[j] : b_ed1[j];
    #pragma unroll 8
    for (int k = 0; k < 1600; ++k)
        s = fmaf(embT[k * 64 + b], W1[k * 256 + j], s);
    hid[(head * 256 + j) * 64 + b] = fmaxf(s, 0.f);
}

// ---------------- kernel D2: second FC layer (3 cols) + sigmoid product ---
__global__ __launch_bounds__(256) void k_fc2(
    const float* __restrict__ hid,
    const float* __restrict__ w_ed2, const float* __restrict__ b_ed2,
    const float* __restrict__ w_ep2, const float* __restrict__ b_ep2,
    const int* __restrict__ esrc, const int* __restrict__ edst,
    float* __restrict__ out)
{
    __shared__ float sl[192];
    int t = threadIdx.x;
    if (t < 192) {
        int q = __builtin_amdgcn_readfirstlane(t >> 6);
        int b = t & 63;
        int c0 = esrc[0], c1 = edst[0];
        int head = (q > 0) ? 1 : 0;
        float acc = 0.f;
        #pragma unroll 4
        for (int j = 0; j < 256; ++j) {
            float w = (q == 0) ? w_ed2[j * 120]
                    : (q == 1) ? w_ep2[j * 36 + c0]
                               : w_ep2[j * 36 + c1];
            acc = fmaf(hid[(head * 256 + j) * 64 + b], w, acc);
        }
        float bias = (q == 0) ? b_ed2[0] : (q == 1) ? b_ep2[c0] : b_ep2[c1];
        sl[q * 64 + b] = 1.f / (1.f + expf(-(acc + bias)));
    }
    __syncthreads();
    if (t < 64) out[t] = sl[t] * sl[64 + t] * sl[128 + t];
}

// ---------------- launch --------------------------------------------------
extern "C" void kernel_launch(void* const* d_in, const int* in_sizes, int n_in,
                              void* d_out, int out_size, void* d_ws, size_t ws_size,
                              hipStream_t stream)
{
    const float* x     = (const float*)d_in[0];
    const float* w1    = (const float*)d_in[1];
    const float* b1    = (const float*)d_in[2];
    const float* w2    = (const float*)d_in[3];
    const float* b2    = (const float*)d_in[4];
    const float* w3    = (const float*)d_in[5];
    const float* b3    = (const float*)d_in[6];
    const float* w4    = (const float*)d_in[7];
    const float* b4    = (const float*)d_in[8];
    const float* w_ed1 = (const float*)d_in[9];
    const float* b_ed1 = (const float*)d_in[10];
    const float* w_ed2 = (const float*)d_in[11];
    const float* b_ed2 = (const float*)d_in[12];
    const float* w_ep1 = (const float*)d_in[13];
    const float* b_ep1 = (const float*)d_in[14];
    const float* w_ep2 = (const float*)d_in[15];
    const float* b_ep2 = (const float*)d_in[16];
    const int*   esrc  = (const int*)d_in[17];
    const int*   edst  = (const int*)d_in[18];

    float* ws  = (float*)d_ws;
    float* out = (float*)d_out;

    k_prep12<<<32, 128, 0, stream>>>(w1, b1, w2, b2, ws + WS_W12, ws + WS_B12);
    k_prep34p<<<64, 256, 0, stream>>>(w3, b3, w4, ws + WS_WPART, ws + WS_BPART);
    k_prep34s<<<649, 256, 0, stream>>>(ws + WS_WPART, ws + WS_BPART, b4,
                                       ws + WS_W34, ws + WS_B34);
    k_conv12<<<64 * 30, 256, 0, stream>>>(x, ws + WS_W12, ws + WS_B12, ws + WS_P1);
    k_conv34<<<640, 320, 0, stream>>>(ws + WS_P1, ws + WS_W34, ws + WS_B34,
                                      ws + WS_EMBT);
    k_fc1<<<128, 256, 0, stream>>>(ws + WS_EMBT, w_ed1, b_ed1, w_ep1, b_ep1,
                                   ws + WS_HID);
    k_fc2<<<1, 256, 0, stream>>>(ws + WS_HID, w_ed2, b_ed2, w_ep2, b_ep2,
                                 esrc, edst, out);
}

// Round 8
// 356.773 us; speedup vs baseline: 4.2533x; 1.0149x over previous
//
#include <hip/hip_runtime.h>
#include <math.h>

// ---------------- workspace layout (floats) ----------------
#define WS_W12   0                         // [9*9][32]        = 2592
#define WS_B12   2592                      // 32
#define WS_W34   2624                      // [32*81][64]      = 165888
#define WS_B34   (2624 + 165888)           // 64
#define WS_P1    (WS_B34 + 64)             // [2][64][30][30][16] = 1843200
#define WS_EMBT  (WS_P1 + 64*30*30*32)     // [1600][64]       = 102400
// overlays (lifetimes disjoint from P1):
#define WS_WPART WS_P1                     // [8][165888] (before conv12)
#define WS_BPART (WS_P1 + 8*165888)        // [8][64]
#define WS_HID   WS_P1                     // [2*256][64] (after conv34)

#define SPLANE 388                         // icl plane stride (4*388%32==16: 2-way)
#define SPH    (16 * SPLANE)               // 6208

// ---------------- kernel A1: compose conv1*conv2 -> 9x9, 1->32ch ----------
__global__ __launch_bounds__(128) void k_prep12(
    const float* __restrict__ w1, const float* __restrict__ b1,
    const float* __restrict__ w2, const float* __restrict__ b2,
    float* __restrict__ W12, float* __restrict__ B12)
{
    __shared__ float sW2[800];
    __shared__ float sW1[800];
    int oc = blockIdx.x;
    int t  = threadIdx.x;
    for (int i = t; i < 800; i += 128) {
        sW2[i] = w2[oc * 800 + i];
        sW1[i] = w1[i];
    }
    __syncthreads();
    if (t < 81) {
        int u = t / 9, v = t % 9;
        float acc[4] = {0.f, 0.f, 0.f, 0.f};
        #pragma unroll
        for (int e = 0; e < 25; ++e) {
            int ey = e / 5, ex = e % 5;
            int du = u - ey, dv = v - ex;
            if ((unsigned)du <= 4u && (unsigned)dv <= 4u) {
                int ep = du * 5 + dv;
                for (int mc = 0; mc < 32; ++mc)
                    acc[e & 3] = fmaf(sW2[mc * 25 + e], sW1[mc * 25 + ep],
                                      acc[e & 3]);
            }
        }
        W12[t * 32 + oc] = (acc[0] + acc[1]) + (acc[2] + acc[3]);
    }
    if (t < 32) {
        float ws = 0.f;
        #pragma unroll
        for (int e = 0; e < 25; ++e) ws += sW2[t * 25 + e];
        float p = b1[t] * ws;
        #pragma unroll
        for (int off = 16; off; off >>= 1) p += __shfl_down(p, off, 64);
        if (t == 0) B12[oc] = p + b2[oc];
    }
}

// ---------------- kernel A2a: conv3*conv4 partials (register outer product)
__global__ __launch_bounds__(256) void k_prep34p(
    const float* __restrict__ w3, const float* __restrict__ b3,
    const float* __restrict__ w4,
    float* __restrict__ Wpart, float* __restrict__ Bpart)
{
    __shared__ float sW3c[800];            // [mcl 8][icl 4][e 25]
    int icg = blockIdx.x >> 3;
    int mcc = blockIdx.x & 7;
    int t   = threadIdx.x;
    int oc  = t & 63;
    int icl = t >> 6;                      // wave-uniform
    int ic  = icg * 4 + icl;

    for (int i = t; i < 800; i += 256) {
        int mcl = i / 100, r = i % 100;
        sW3c[i] = w3[(mcc * 8 + mcl) * 800 + icg * 100 + r];
    }
    __syncthreads();

    float acc[81];
    #pragma unroll
    for (int u = 0; u < 81; ++u) acc[u] = 0.f;
    float bacc = 0.f;

    for (int mcl = 0; mcl < 8; ++mcl) {
        int mc = mcc * 8 + mcl;
        float w4r[25];
        #pragma unroll
        for (int e = 0; e < 25; ++e) w4r[e] = w4[oc * 1600 + mc * 25 + e];
        const float* w3r = &sW3c[(mcl * 4 + icl) * 25];
        #pragma unroll
        for (int e2 = 0; e2 < 25; ++e2) {
            int ey = e2 / 5, ex = e2 % 5;
            #pragma unroll
            for (int e1 = 0; e1 < 25; ++e1) {
                int u = (ey + e1 / 5) * 9 + (ex + e1 % 5);   // compile-time
                acc[u] = fmaf(w4r[e2], w3r[e1], acc[u]);
            }
        }
        if (icl == 0) {
            float ws = 0.f;
            #pragma unroll
            for (int e = 0; e < 25; ++e) ws += w4r[e];
            bacc = fmaf(b3[mc], ws, bacc);
        }
    }

    for (int uv = 0; uv < 81; ++uv)
        Wpart[((mcc * 32 + ic) * 81 + uv) * 64 + oc] = acc[uv];
    if (icl == 0) Bpart[mcc * 64 + oc] = bacc;
}

// ---------------- kernel A2b: sum partials ------------------------------
__global__ __launch_bounds__(256) void k_prep34s(
    const float* __restrict__ Wpart, const float* __restrict__ Bpart,
    const float* __restrict__ b4,
    float* __restrict__ W34, float* __restrict__ B34)
{
    int i = blockIdx.x * 256 + threadIdx.x;
    if (i < 165888) {
        float s = 0.f;
        #pragma unroll
        for (int c = 0; c < 8; ++c) s += Wpart[c * 165888 + i];
        W34[i] = s;
    }
    if (blockIdx.x == 648 && threadIdx.x < 64) {
        int oc = threadIdx.x;
        float s = b4[oc];
        #pragma unroll
        for (int c = 0; c < 8; ++c) s += Bpart[c * 64 + oc];
        B34[oc] = s;
    }
}

// ---------------- kernel B: fused 9x9 conv12 + 4x4 maxpool ----------------
// P1 layout: [ph=oc>>4][b][row][col][icl=oc&15]
__global__ __launch_bounds__(256) void k_conv12(
    const float* __restrict__ x, const float* __restrict__ W12,
    const float* __restrict__ B12, float* __restrict__ P1)
{
    __shared__ float sIn[12][128];

    int b  = blockIdx.x / 30;
    int py = blockIdx.x % 30;
    int t  = threadIdx.x;

    const float* xb = x + b * 128 * 128;
    for (int i = t; i < 12 * 32; i += 256) {
        int row = i >> 5, c4 = i & 31;
        ((float4*)sIn[row])[c4] =
            ((const float4*)(xb + (4 * py + row) * 128))[c4];
    }

    int oc = t & 31;
    int pg = t >> 5;
    float w[81];
    #pragma unroll
    for (int e = 0; e < 81; ++e) w[e] = W12[e * 32 + oc];
    float bias = B12[oc];
    __syncthreads();

    int ph  = oc >> 4;
    int icl = oc & 15;

    for (int j = 0; j < 4; ++j) {
        int px = pg + 8 * j;
        if (px >= 30) break;
        float acc[4][4];
        #pragma unroll
        for (int iy = 0; iy < 4; ++iy)
            #pragma unroll
            for (int ix = 0; ix < 4; ++ix) acc[iy][ix] = 0.f;

        #pragma unroll
        for (int r = 0; r < 12; ++r) {
            const float* rp = sIn[r] + 4 * px;
            float4 A  = ((const float4*)rp)[0];
            float4 Bq = ((const float4*)rp)[1];
            float4 Cq = ((const float4*)rp)[2];
            float win[12] = {A.x, A.y, A.z, A.w, Bq.x, Bq.y, Bq.z, Bq.w,
                             Cq.x, Cq.y, Cq.z, Cq.w};
            #pragma unroll
            for (int iy = 0; iy < 4; ++iy) {
                int ky = r - iy;
                if (ky < 0 || ky > 8) continue;
                #pragma unroll
                for (int ix = 0; ix < 4; ++ix)
                    #pragma unroll
                    for (int kx = 0; kx < 9; ++kx)
                        acc[iy][ix] = fmaf(w[ky * 9 + kx], win[ix + kx],
                                           acc[iy][ix]);
            }
        }
        float m = -INFINITY;
        #pragma unroll
        for (int iy = 0; iy < 4; ++iy)
            #pragma unroll
            for (int ix = 0; ix < 4; ++ix) m = fmaxf(m, acc[iy][ix]);
        P1[((((ph * 64 + b) * 30 + py) * 30 + px) * 16) + icl] = m + bias;
    }
}

// ---------------- kernel C: fused 9x9 conv34 + 4x4 maxpool ----------------
// grid = (b,py,oh) = 640; block = 640 = 2 ph * (32 ocl * 10 grp).
// Both 16-ic phases staged & computed CONCURRENTLY by block halves;
// partials combined via LDS reduce before pool-max. 10-wave blocks,
// 49.8 KB LDS -> up to 3 blocks/CU, ~25 resident waves/CU.
// Weight rows software-pipelined through a rotating wrow[3] buffer.
__global__ __launch_bounds__(640) void k_conv34(
    const float* __restrict__ P1, const float* __restrict__ W34,
    const float* __restrict__ B34, float* __restrict__ embT)
{
    __shared__ float sIn[2 * SPH];      // 49.7 KB, [ph][icl][row12][col pad]
    __shared__ float sPool[10][32];

    int bi = blockIdx.x;
    int oh = bi & 1;
    int bp = bi >> 1;
    int b  = bp / 5;
    int py = bp % 5;
    int t  = threadIdx.x;

    int ph = (t >= 320) ? 1 : 0;          // wave-uniform (waves 0-4 / 5-9)
    int t3 = t - ph * 320;                // 0..319

    // ---- stage this half's 16 ic: contiguous [12][30][16] span ----
    {
        const float4* src = (const float4*)(P1 +
            (((ph * 64 + b) * 30 + 4 * py) * 30) * 16);
        float* dst = sIn + ph * SPH;
        for (int i = t3; i < 1440; i += 320) {
            float4 v = src[i];
            int icq = i & 3;
            int rc  = i >> 2;
            int row = rc / 30, col = rc % 30;
            int base = row * 32 + col;
            dst[(icq * 4 + 0) * SPLANE + base] = v.x;
            dst[(icq * 4 + 1) * SPLANE + base] = v.y;
            dst[(icq * 4 + 2) * SPLANE + base] = v.z;
            dst[(icq * 4 + 3) * SPLANE + base] = v.w;
        }
    }
    __syncthreads();

    int ocl  = t3 & 31;
    int oc   = ocl + (oh << 5);
    int grp  = t3 >> 5;           // 0..9
    int iyh  = grp / 5;
    int cgrp = grp % 5;

    float acc[2][4];
    #pragma unroll
    for (int d = 0; d < 2; ++d)
        #pragma unroll
        for (int ix = 0; ix < 4; ++ix) acc[d][ix] = 0.f;

    const float* phIn = sIn + ph * SPH;

    for (int icl = 0; icl < 16; ++icl) {
        int ic = ph * 16 + icl;
        const float* slab = phIn + icl * SPLANE;
        const float* Wb   = W34 + ic * 81 * 64 + oc;

        float wrow[3][9];
        #pragma unroll
        for (int kx = 0; kx < 9; ++kx) wrow[0][kx] = Wb[kx * 64];

        #pragma unroll
        for (int ro = 0; ro < 10; ++ro) {
            if (ro <= 7) {                 // prefetch row ro+1 (slots distinct mod 3)
                #pragma unroll
                for (int kx = 0; kx < 9; ++kx)
                    wrow[(ro + 1) % 3][kx] = Wb[((ro + 1) * 9 + kx) * 64];
            }
            const float* rp = slab + (2 * iyh + ro) * 32 + 4 * cgrp;
            float4 A  = ((const float4*)rp)[0];
            float4 Bq = ((const float4*)rp)[1];
            float4 Cq = ((const float4*)rp)[2];
            float win[12] = {A.x, A.y, A.z, A.w, Bq.x, Bq.y, Bq.z, Bq.w,
                             Cq.x, Cq.y, Cq.z, Cq.w};
            if (ro <= 8) {                 // d=0, ky=ro
                const float* wk = wrow[ro % 3];
                #pragma unroll
                for (int ix = 0; ix < 4; ++ix)
                    #pragma unroll
                    for (int kx = 0; kx < 9; ++kx)
                        acc[0][ix] = fmaf(wk[kx], win[ix + kx], acc[0][ix]);
            }
            if (ro >= 1) {                 // d=1, ky=ro-1
                const float* wk = wrow[(ro - 1) % 3];
                #pragma unroll
                for (int ix = 0; ix < 4; ++ix)
                    #pragma unroll
                    for (int kx = 0; kx < 9; ++kx)
                        acc[1][ix] = fmaf(wk[kx], win[ix + kx], acc[1][ix]);
            }
        }
    }

    // ---- cross-ph reduction (reuse sIn), then pool ----
    __syncthreads();
    float* sRed = sIn;                     // stride 9 -> 2-way only
    if (ph == 1) {
        #pragma unroll
        for (int d = 0; d < 2; ++d)
            #pragma unroll
            for (int ix = 0; ix < 4; ++ix)
                sRed[t3 * 9 + d * 4 + ix] = acc[d][ix];
    }
    __syncthreads();
    if (ph == 0) {
        float pmax = -INFINITY;
        #pragma unroll
        for (int d = 0; d < 2; ++d)
            #pragma unroll
            for (int ix = 0; ix < 4; ++ix)
                pmax = fmaxf(pmax, acc[d][ix] + sRed[t3 * 9 + d * 4 + ix]);
        sPool[grp][ocl] = pmax;
    }
    __syncthreads();

    if (ph == 0 && grp < 5) {
        float m = fmaxf(sPool[grp][ocl], sPool[grp + 5][ocl]) + B34[oc];
        embT[(oc * 25 + py * 5 + grp) * 64 + b] = m;
    }
}

// ---------------- kernel D1: first FC layer, both heads -------------------
__global__ __launch_bounds__(256) void k_fc1(
    const float* __restrict__ embT,
    const float* __restrict__ w_ed1, const float* __restrict__ b_ed1,
    const float* __restrict__ w_ep1, const float* __restrict__ b_ep1,
    float* __restrict__ hid)
{
    int head = blockIdx.x >> 6;
    int jg   = blockIdx.x & 63;
    int b    = threadIdx.x & 63;
    int jl   = __builtin_amdgcn_readfirstlane(threadIdx.x >> 6);
    int j    = jg * 4 + jl;

    const float* W1 = head ? w_ep1 : w_ed1;
    float s = head ? b_ep1[j] : b_ed1[j];
    #pragma unroll 8
    for (int k = 0; k < 1600; ++k)
        s = fmaf(embT[k * 64 + b], W1[k * 256 + j], s);
    hid[(head * 256 + j) * 64 + b] = fmaxf(s, 0.f);
}

// ---------------- kernel D2: second FC layer (3 cols) + sigmoid product ---
__global__ __launch_bounds__(256) void k_fc2(
    const float* __restrict__ hid,
    const float* __restrict__ w_ed2, const float* __restrict__ b_ed2,
    const float* __restrict__ w_ep2, const float* __restrict__ b_ep2,
    const int* __restrict__ esrc, const int* __restrict__ edst,
    float* __restrict__ out)
{
    __shared__ float sl[192];
    int t = threadIdx.x;
    if (t < 192) {
        int q = __builtin_amdgcn_readfirstlane(t >> 6);
        int b = t & 63;
        int c0 = esrc[0], c1 = edst[0];
        int head = (q > 0) ? 1 : 0;
        float acc = 0.f;
        #pragma unroll 4
        for (int j = 0; j < 256; ++j) {
            float w = (q == 0) ? w_ed2[j * 120]
                    : (q == 1) ? w_ep2[j * 36 + c0]
                               : w_ep2[j * 36 + c1];
            acc = fmaf(hid[(head * 256 + j) * 64 + b], w, acc);
        }
        float bias = (q == 0) ? b_ed2[0] : (q == 1) ? b_ep2[c0] : b_ep2[c1];
        sl[q * 64 + b] = 1.f / (1.f + expf(-(acc + bias)));
    }
    __syncthreads();
    if (t < 64) out[t] = sl[t] * sl[64 + t] * sl[128 + t];
}

// ---------------- launch --------------------------------------------------
extern "C" void kernel_launch(void* const* d_in, const int* in_sizes, int n_in,
                              void* d_out, int out_size, void* d_ws, size_t ws_size,
                              hipStream_t stream)
{
    const float* x     = (const float*)d_in[0];
    const float* w1    = (const float*)d_in[1];
    const float* b1    = (const float*)d_in[2];
    const float* w2    = (const float*)d_in[3];
    const float* b2    = (const float*)d_in[4];
    const float* w3    = (const float*)d_in[5];
    const float* b3    = (const float*)d_in[6];
    const float* w4    = (const float*)d_in[7];
    const float* b4    = (const float*)d_in[8];
    const float* w_ed1 = (const float*)d_in[9];
    const float* b_ed1 = (const float*)d_in[10];
    const float* w_ed2 = (const float*)d_in[11];
    const float* b_ed2 = (const float*)d_in[12];
    const float* w_ep1 = (const float*)d_in[13];
    const float* b_ep1 = (const float*)d_in[14];
    const float* w_ep2 = (const float*)d_in[15];
    const float* b_ep2 = (const float*)d_in[16];
    const int*   esrc  = (const int*)d_in[17];
    const int*   edst  = (const int*)d_in[18];

    float* ws  = (float*)d_ws;
    float* out = (float*)d_out;

    k_prep12<<<32, 128, 0, stream>>>(w1, b1, w2, b2, ws + WS_W12, ws + WS_B12);
    k_prep34p<<<64, 256, 0, stream>>>(w3, b3, w4, ws + WS_WPART, ws + WS_BPART);
    k_prep34s<<<649, 256, 0, stream>>>(ws + WS_WPART, ws + WS_BPART, b4,
                                       ws + WS_W34, ws + WS_B34);
    k_conv12<<<64 * 30, 256, 0, stream>>>(x, ws + WS_W12, ws + WS_B12, ws + WS_P1);
    k_conv34<<<640, 640, 0, stream>>>(ws + WS_P1, ws + WS_W34, ws + WS_B34,
                                      ws + WS_EMBT);
    k_fc1<<<128, 256, 0, stream>>>(ws + WS_EMBT, w_ed1, b_ed1, w_ep1, b_ep1,
                                   ws + WS_HID);
    k_fc2<<<1, 256, 0, stream>>>(ws + WS_HID, w_ed2, b_ed2, w_ep2, b_ep2,
                                 esrc, edst, out);
}

// Round 9
// 351.294 us; speedup vs baseline: 4.3196x; 1.0156x over previous
//
#include <hip/hip_runtime.h>
#include <math.h>

// ---------------- workspace layout (floats) ----------------
#define WS_W12   0                         // [9*9][32]        = 2592
#define WS_B12   2592                      // 32
#define WS_W34   2624                      // [32*81][64]      = 165888
#define WS_B34   (2624 + 165888)           // 64
#define WS_P1    (WS_B34 + 64)             // [2][64][30][30][16] = 1843200
#define WS_EMBT  (WS_P1 + 64*30*30*32)     // [1600][64]       = 102400
// overlays (lifetimes disjoint from P1):
#define WS_WPART WS_P1                     // [8][165888] (before conv12)
#define WS_BPART (WS_P1 + 8*165888)        // [8][64]
#define WS_HID   WS_P1                     // [2*256][64] (after conv34)

#define SPLANE 388                         // icl plane stride (4*388%32==16: 2-way)
#define SPH    (16 * SPLANE)               // 6208

// ---------------- kernel A1: compose conv1*conv2 -> 9x9, 1->32ch ----------
__global__ __launch_bounds__(128) void k_prep12(
    const float* __restrict__ w1, const float* __restrict__ b1,
    const float* __restrict__ w2, const float* __restrict__ b2,
    float* __restrict__ W12, float* __restrict__ B12)
{
    __shared__ float sW2[800];
    __shared__ float sW1[800];
    int oc = blockIdx.x;
    int t  = threadIdx.x;
    for (int i = t; i < 800; i += 128) {
        sW2[i] = w2[oc * 800 + i];
        sW1[i] = w1[i];
    }
    __syncthreads();
    if (t < 81) {
        int u = t / 9, v = t % 9;
        float acc[4] = {0.f, 0.f, 0.f, 0.f};
        #pragma unroll
        for (int e = 0; e < 25; ++e) {
            int ey = e / 5, ex = e % 5;
            int du = u - ey, dv = v - ex;
            if ((unsigned)du <= 4u && (unsigned)dv <= 4u) {
                int ep = du * 5 + dv;
                for (int mc = 0; mc < 32; ++mc)
                    acc[e & 3] = fmaf(sW2[mc * 25 + e], sW1[mc * 25 + ep],
                                      acc[e & 3]);
            }
        }
        W12[t * 32 + oc] = (acc[0] + acc[1]) + (acc[2] + acc[3]);
    }
    if (t < 32) {
        float ws = 0.f;
        #pragma unroll
        for (int e = 0; e < 25; ++e) ws += sW2[t * 25 + e];
        float p = b1[t] * ws;
        #pragma unroll
        for (int off = 16; off; off >>= 1) p += __shfl_down(p, off, 64);
        if (t == 0) B12[oc] = p + b2[oc];
    }
}

// ---------------- kernel A2a: conv3*conv4 partials (register outer product)
__global__ __launch_bounds__(256) void k_prep34p(
    const float* __restrict__ w3, const float* __restrict__ b3,
    const float* __restrict__ w4,
    float* __restrict__ Wpart, float* __restrict__ Bpart)
{
    __shared__ float sW3c[800];            // [mcl 8][icl 4][e 25]
    int icg = blockIdx.x >> 3;
    int mcc = blockIdx.x & 7;
    int t   = threadIdx.x;
    int oc  = t & 63;
    int icl = t >> 6;                      // wave-uniform
    int ic  = icg * 4 + icl;

    for (int i = t; i < 800; i += 256) {
        int mcl = i / 100, r = i % 100;
        sW3c[i] = w3[(mcc * 8 + mcl) * 800 + icg * 100 + r];
    }
    __syncthreads();

    float acc[81];
    #pragma unroll
    for (int u = 0; u < 81; ++u) acc[u] = 0.f;
    float bacc = 0.f;

    for (int mcl = 0; mcl < 8; ++mcl) {
        int mc = mcc * 8 + mcl;
        float w4r[25];
        #pragma unroll
        for (int e = 0; e < 25; ++e) w4r[e] = w4[oc * 1600 + mc * 25 + e];
        const float* w3r = &sW3c[(mcl * 4 + icl) * 25];
        #pragma unroll
        for (int e2 = 0; e2 < 25; ++e2) {
            int ey = e2 / 5, ex = e2 % 5;
            #pragma unroll
            for (int e1 = 0; e1 < 25; ++e1) {
                int u = (ey + e1 / 5) * 9 + (ex + e1 % 5);   // compile-time
                acc[u] = fmaf(w4r[e2], w3r[e1], acc[u]);
            }
        }
        if (icl == 0) {
            float ws = 0.f;
            #pragma unroll
            for (int e = 0; e < 25; ++e) ws += w4r[e];
            bacc = fmaf(b3[mc], ws, bacc);
        }
    }

    for (int uv = 0; uv < 81; ++uv)
        Wpart[((mcc * 32 + ic) * 81 + uv) * 64 + oc] = acc[uv];
    if (icl == 0) Bpart[mcc * 64 + oc] = bacc;
}

// ---------------- kernel A2b: sum partials ------------------------------
__global__ __launch_bounds__(256) void k_prep34s(
    const float* __restrict__ Wpart, const float* __restrict__ Bpart,
    const float* __restrict__ b4,
    float* __restrict__ W34, float* __restrict__ B34)
{
    int i = blockIdx.x * 256 + threadIdx.x;
    if (i < 165888) {
        float s = 0.f;
        #pragma unroll
        for (int c = 0; c < 8; ++c) s += Wpart[c * 165888 + i];
        W34[i] = s;
    }
    if (blockIdx.x == 648 && threadIdx.x < 64) {
        int oc = threadIdx.x;
        float s = b4[oc];
        #pragma unroll
        for (int c = 0; c < 8; ++c) s += Bpart[c * 64 + oc];
        B34[oc] = s;
    }
}

// ---------------- kernel B: fused 9x9 conv12 + 4x4 maxpool ----------------
// P1 layout: [ph=oc>>4][b][row][col][icl=oc&15]
__global__ __launch_bounds__(256) void k_conv12(
    const float* __restrict__ x, const float* __restrict__ W12,
    const float* __restrict__ B12, float* __restrict__ P1)
{
    __shared__ float sIn[12][128];

    int b  = blockIdx.x / 30;
    int py = blockIdx.x % 30;
    int t  = threadIdx.x;

    const float* xb = x + b * 128 * 128;
    for (int i = t; i < 12 * 32; i += 256) {
        int row = i >> 5, c4 = i & 31;
        ((float4*)sIn[row])[c4] =
            ((const float4*)(xb + (4 * py + row) * 128))[c4];
    }

    int oc = t & 31;
    int pg = t >> 5;
    float w[81];
    #pragma unroll
    for (int e = 0; e < 81; ++e) w[e] = W12[e * 32 + oc];
    float bias = B12[oc];
    __syncthreads();

    int ph  = oc >> 4;
    int icl = oc & 15;

    for (int j = 0; j < 4; ++j) {
        int px = pg + 8 * j;
        if (px >= 30) break;
        float acc[4][4];
        #pragma unroll
        for (int iy = 0; iy < 4; ++iy)
            #pragma unroll
            for (int ix = 0; ix < 4; ++ix) acc[iy][ix] = 0.f;

        #pragma unroll
        for (int r = 0; r < 12; ++r) {
            const float* rp = sIn[r] + 4 * px;
            float4 A  = ((const float4*)rp)[0];
            float4 Bq = ((const float4*)rp)[1];
            float4 Cq = ((const float4*)rp)[2];
            float win[12] = {A.x, A.y, A.z, A.w, Bq.x, Bq.y, Bq.z, Bq.w,
                             Cq.x, Cq.y, Cq.z, Cq.w};
            #pragma unroll
            for (int iy = 0; iy < 4; ++iy) {
                int ky = r - iy;
                if (ky < 0 || ky > 8) continue;
                #pragma unroll
                for (int ix = 0; ix < 4; ++ix)
                    #pragma unroll
                    for (int kx = 0; kx < 9; ++kx)
                        acc[iy][ix] = fmaf(w[ky * 9 + kx], win[ix + kx],
                                           acc[iy][ix]);
            }
        }
        float m = -INFINITY;
        #pragma unroll
        for (int iy = 0; iy < 4; ++iy)
            #pragma unroll
            for (int ix = 0; ix < 4; ++ix) m = fmaxf(m, acc[iy][ix]);
        P1[((((ph * 64 + b) * 30 + py) * 30 + px) * 16) + icl] = m + bias;
    }
}

// ---------------- kernel C: fused 9x9 conv34 + 4x4 maxpool ----------------
// grid = (b,py,oh) = 640; block = 320 = 32 ocl * 5 cgrp * 2 ph.
// Each thread owns a FULL 4x4 pool cell (16 acc): halves DS + weight-load
// instrs per FMA vs R8. Weight rows via 5-slot rotating register buffer
// (prefetched 1 row ahead, all indices compile-time). Both ic-phases run
// concurrently in block halves; cross-ph LDS reduce then pool-max.
__global__ __launch_bounds__(320, 4) void k_conv34(
    const float* __restrict__ P1, const float* __restrict__ W34,
    const float* __restrict__ B34, float* __restrict__ embT)
{
    __shared__ float sIn[2 * SPH];      // 49.7 KB, [ph][icl][row12][col pad]

    int bi = blockIdx.x;
    int oh = bi & 1;
    int bp = bi >> 1;
    int b  = bp / 5;
    int py = bp % 5;
    int t  = threadIdx.x;

    int ocl  = t & 31;
    int rest = t >> 5;            // 0..9
    int cgrp = rest % 5;
    int ph   = rest / 5;
    int oc   = ocl + (oh << 5);

    // ---- stage this half's 16 ic: contiguous [12][30][16] span ----
    {
        int t3s = t - ph * 160;   // 0..159
        const float4* src = (const float4*)(P1 +
            (((ph * 64 + b) * 30 + 4 * py) * 30) * 16);
        float* dst = sIn + ph * SPH;
        for (int i = t3s; i < 1440; i += 160) {
            float4 v = src[i];
            int icq = i & 3;
            int rc  = i >> 2;
            int row = rc / 30, col = rc % 30;
            int base = row * 32 + col;
            dst[(icq * 4 + 0) * SPLANE + base] = v.x;
            dst[(icq * 4 + 1) * SPLANE + base] = v.y;
            dst[(icq * 4 + 2) * SPLANE + base] = v.z;
            dst[(icq * 4 + 3) * SPLANE + base] = v.w;
        }
    }
    __syncthreads();

    float acc[4][4];              // [iy][ix] — full pool cell
    #pragma unroll
    for (int iy = 0; iy < 4; ++iy)
        #pragma unroll
        for (int ix = 0; ix < 4; ++ix) acc[iy][ix] = 0.f;

    const float* phIn = sIn + ph * SPH;

    for (int icl = 0; icl < 16; ++icl) {
        const float* slab = phIn + icl * SPLANE;
        const float* Wb   = W34 + (ph * 16 + icl) * 81 * 64 + oc;

        float wr[5][9];           // rotating: slot k%5 holds weight row k
        #pragma unroll
        for (int kx = 0; kx < 9; ++kx) wr[0][kx] = Wb[kx * 64];

        #pragma unroll
        for (int ro = 0; ro < 12; ++ro) {        // staged input rows
            if (ro <= 7) {                       // prefetch row ro+1
                #pragma unroll
                for (int kx = 0; kx < 9; ++kx)
                    wr[(ro + 1) % 5][kx] = Wb[((ro + 1) * 9 + kx) * 64];
            }
            const float* rp = slab + ro * 32 + 4 * cgrp;
            float4 A  = ((const float4*)rp)[0];
            float4 Bq = ((const float4*)rp)[1];
            float4 Cq = ((const float4*)rp)[2];
            float win[12] = {A.x, A.y, A.z, A.w, Bq.x, Bq.y, Bq.z, Bq.w,
                             Cq.x, Cq.y, Cq.z, Cq.w};
            #pragma unroll
            for (int iy = 0; iy < 4; ++iy) {
                int ky = ro - iy;                // compile-time after unroll
                if (ky < 0 || ky > 8) continue;
                const float* wk = wr[ky % 5];    // compile-time slot
                #pragma unroll
                for (int ix = 0; ix < 4; ++ix)
                    #pragma unroll
                    for (int kx = 0; kx < 9; ++kx)
                        acc[iy][ix] = fmaf(wk[kx], win[ix + kx],
                                           acc[iy][ix]);
            }
        }
    }

    // ---- cross-ph reduction (reuse sIn), then pool-max ----
    __syncthreads();
    float* sRed = sIn;                     // stride 17 -> conflict-free
    if (ph == 1) {
        int t3 = t - 160;
        #pragma unroll
        for (int iy = 0; iy < 4; ++iy)
            #pragma unroll
            for (int ix = 0; ix < 4; ++ix)
                sRed[t3 * 17 + iy * 4 + ix] = acc[iy][ix];
    }
    __syncthreads();
    if (ph == 0) {
        float pmax = -INFINITY;
        #pragma unroll
        for (int iy = 0; iy < 4; ++iy)
            #pragma unroll
            for (int ix = 0; ix < 4; ++ix)
                pmax = fmaxf(pmax, acc[iy][ix] + sRed[t * 17 + iy * 4 + ix]);
        embT[(oc * 25 + py * 5 + cgrp) * 64 + b] = pmax + B34[oc];
    }
}

// ---------------- kernel D1: first FC layer, both heads -------------------
__global__ __launch_bounds__(256) void k_fc1(
    const float* __restrict__ embT,
    const float* __restrict__ w_ed1, const float* __restrict__ b_ed1,
    const float* __restrict__ w_ep1, const float* __restrict__ b_ep1,
    float* __restrict__ hid)
{
    int head = blockIdx.x >> 6;
    int jg   = blockIdx.x & 63;
    int b    = threadIdx.x & 63;
    int jl   = __builtin_amdgcn_readfirstlane(threadIdx.x >> 6);
    int j    = jg * 4 + jl;

    const float* W1 = head ? w_ep1 : w_ed1;
    float s = head ? b_ep1[j] : b_ed1[j];
    #pragma unroll 8
    for (int k = 0; k < 1600; ++k)
        s = fmaf(embT[k * 64 + b], W1[k * 256 + j], s);
    hid[(head * 256 + j) * 64 + b] = fmaxf(s, 0.f);
}

// ---------------- kernel D2: second FC layer (3 cols) + sigmoid product ---
__global__ __launch_bounds__(256) void k_fc2(
    const float* __restrict__ hid,
    const float* __restrict__ w_ed2, const float* __restrict__ b_ed2,
    const float* __restrict__ w_ep2, const float* __restrict__ b_ep2,
    const int* __restrict__ esrc, const int* __restrict__ edst,
    float* __restrict__ out)
{
    __shared__ float sl[192];
    int t = threadIdx.x;
    if (t < 192) {
        int q = __builtin_amdgcn_readfirstlane(t >> 6);
        int b = t & 63;
        int c0 = esrc[0], c1 = edst[0];
        int head = (q > 0) ? 1 : 0;
        float acc = 0.f;
        #pragma unroll 4
        for (int j = 0; j < 256; ++j) {
            float w = (q == 0) ? w_ed2[j * 120]
                    : (q == 1) ? w_ep2[j * 36 + c0]
                               : w_ep2[j * 36 + c1];
            acc = fmaf(hid[(head * 256 + j) * 64 + b], w, acc);
        }
        float bias = (q == 0) ? b_ed2[0] : (q == 1) ? b_ep2[c0] : b_ep2[c1];
        sl[q * 64 + b] = 1.f / (1.f + expf(-(acc + bias)));
    }
    __syncthreads();
    if (t < 64) out[t] = sl[t] * sl[64 + t] * sl[128 + t];
}

// ---------------- launch --------------------------------------------------
extern "C" void kernel_launch(void* const* d_in, const int* in_sizes, int n_in,
                              void* d_out, int out_size, void* d_ws, size_t ws_size,
                              hipStream_t stream)
{
    const float* x     = (const float*)d_in[0];
    const float* w1    = (const float*)d_in[1];
    const float* b1    = (const float*)d_in[2];
    const float* w2    = (const float*)d_in[3];
    const float* b2    = (const float*)d_in[4];
    const float* w3    = (const float*)d_in[5];
    const float* b3    = (const float*)d_in[6];
    const float* w4    = (const float*)d_in[7];
    const float* b4    = (const float*)d_in[8];
    const float* w_ed1 = (const float*)d_in[9];
    const float* b_ed1 = (const float*)d_in[10];
    const float* w_ed2 = (const float*)d_in[11];
    const float* b_ed2 = (const float*)d_in[12];
    const float* w_ep1 = (const float*)d_in[13];
    const float* b_ep1 = (const float*)d_in[14];
    const float* w_ep2 = (const float*)d_in[15];
    const float* b_ep2 = (const float*)d_in[16];
    const int*   esrc  = (const int*)d_in[17];
    const int*   edst  = (const int*)d_in[18];

    float* ws  = (float*)d_ws;
    float* out = (float*)d_out;

    k_prep12<<<32, 128, 0, stream>>>(w1, b1, w2, b2, ws + WS_W12, ws + WS_B12);
    k_prep34p<<<64, 256, 0, stream>>>(w3, b3, w4, ws + WS_WPART, ws + WS_BPART);
    k_prep34s<<<649, 256, 0, stream>>>(ws + WS_WPART, ws + WS_BPART, b4,
                                       ws + WS_W34, ws + WS_B34);
    k_conv12<<<64 * 30, 256, 0, stream>>>(x, ws + WS_W12, ws + WS_B12, ws + WS_P1);
    k_conv34<<<640, 320, 0, stream>>>(ws + WS_P1, ws + WS_W34, ws + WS_B34,
                                      ws + WS_EMBT);
    k_fc1<<<128, 256, 0, stream>>>(ws + WS_EMBT, w_ed1, b_ed1, w_ep1, b_ep1,
                                   ws + WS_HID);
    k_fc2<<<1, 256, 0, stream>>>(ws + WS_HID, w_ed2, b_ed2, w_ep2, b_ep2,
                                 esrc, edst, out);
}

// Round 10
// 225.405 us; speedup vs baseline: 6.7322x; 1.5585x over previous
//
#include <hip/hip_runtime.h>
#include <math.h>

typedef __attribute__((ext_vector_type(8))) short bf16x8;
typedef __attribute__((ext_vector_type(4))) float f32x4;
typedef unsigned short ushort_t;

// ---------------- workspace layout (floats) ----------------
#define WS_W12   0                         // [9*9][32]        = 2592
#define WS_B12   2592                      // 32
#define WS_WMF   2624                      // Wmf bf16: 165888 ushort = 82944 float slots
#define WS_B34   (2624 + 165888)           // 64  (leave gap; region is big enough)
#define WS_P1    (WS_B34 + 64)             // P1 bf16: [64][30][30][32] ushort (921600 fl slots)
#define WS_EMBT  (WS_P1 + 64*30*30*32)     // [1600][64] = 102400 floats
// overlays (lifetimes disjoint):
#define WS_WPART WS_P1                     // [8][165888] floats (before conv12)
#define WS_BPART (WS_P1 + 8*165888)        // [8][64]
#define WS_HID   WS_P1                     // [2*256][64] (after conv34)

__device__ __forceinline__ unsigned short f2bf(float f) {
    unsigned u = __float_as_uint(f);
    u += 0x7FFF + ((u >> 16) & 1);         // RNE
    return (unsigned short)(u >> 16);
}

// ---------------- kernel A1: compose conv1*conv2 -> 9x9, 1->32ch ----------
__global__ __launch_bounds__(128) void k_prep12(
    const float* __restrict__ w1, const float* __restrict__ b1,
    const float* __restrict__ w2, const float* __restrict__ b2,
    float* __restrict__ W12, float* __restrict__ B12)
{
    __shared__ float sW2[800];
    __shared__ float sW1[800];
    int oc = blockIdx.x;
    int t  = threadIdx.x;
    for (int i = t; i < 800; i += 128) {
        sW2[i] = w2[oc * 800 + i];
        sW1[i] = w1[i];
    }
    __syncthreads();
    if (t < 81) {
        int u = t / 9, v = t % 9;
        float acc[4] = {0.f, 0.f, 0.f, 0.f};
        #pragma unroll
        for (int e = 0; e < 25; ++e) {
            int ey = e / 5, ex = e % 5;
            int du = u - ey, dv = v - ex;
            if ((unsigned)du <= 4u && (unsigned)dv <= 4u) {
                int ep = du * 5 + dv;
                for (int mc = 0; mc < 32; ++mc)
                    acc[e & 3] = fmaf(sW2[mc * 25 + e], sW1[mc * 25 + ep],
                                      acc[e & 3]);
            }
        }
        W12[t * 32 + oc] = (acc[0] + acc[1]) + (acc[2] + acc[3]);
    }
    if (t < 32) {
        float ws = 0.f;
        #pragma unroll
        for (int e = 0; e < 25; ++e) ws += sW2[t * 25 + e];
        float p = b1[t] * ws;
        #pragma unroll
        for (int off = 16; off; off >>= 1) p += __shfl_down(p, off, 64);
        if (t == 0) B12[oc] = p + b2[oc];
    }
}

// ---------------- kernel A2a: conv3*conv4 partials (register outer product)
__global__ __launch_bounds__(256) void k_prep34p(
    const float* __restrict__ w3, const float* __restrict__ b3,
    const float* __restrict__ w4,
    float* __restrict__ Wpart, float* __restrict__ Bpart)
{
    __shared__ float sW3c[800];            // [mcl 8][icl 4][e 25]
    int icg = blockIdx.x >> 3;
    int mcc = blockIdx.x & 7;
    int t   = threadIdx.x;
    int oc  = t & 63;
    int icl = t >> 6;                      // wave-uniform
    int ic  = icg * 4 + icl;

    for (int i = t; i < 800; i += 256) {
        int mcl = i / 100, r = i % 100;
        sW3c[i] = w3[(mcc * 8 + mcl) * 800 + icg * 100 + r];
    }
    __syncthreads();

    float acc[81];
    #pragma unroll
    for (int u = 0; u < 81; ++u) acc[u] = 0.f;
    float bacc = 0.f;

    for (int mcl = 0; mcl < 8; ++mcl) {
        int mc = mcc * 8 + mcl;
        float w4r[25];
        #pragma unroll
        for (int e = 0; e < 25; ++e) w4r[e] = w4[oc * 1600 + mc * 25 + e];
        const float* w3r = &sW3c[(mcl * 4 + icl) * 25];
        #pragma unroll
        for (int e2 = 0; e2 < 25; ++e2) {
            int ey = e2 / 5, ex = e2 % 5;
            #pragma unroll
            for (int e1 = 0; e1 < 25; ++e1) {
                int u = (ey + e1 / 5) * 9 + (ex + e1 % 5);   // compile-time
                acc[u] = fmaf(w4r[e2], w3r[e1], acc[u]);
            }
        }
        if (icl == 0) {
            float ws = 0.f;
            #pragma unroll
            for (int e = 0; e < 25; ++e) ws += w4r[e];
            bacc = fmaf(b3[mc], ws, bacc);
        }
    }

    for (int uv = 0; uv < 81; ++uv)
        Wpart[((mcc * 32 + ic) * 81 + uv) * 64 + oc] = acc[uv];
    if (icl == 0) Bpart[mcc * 64 + oc] = bacc;
}

// ---------------- kernel A2b: sum partials -> bf16 MFMA-swizzled weights --
// Wmf[tap][nt4][kc4][n16][e8]: value = W34[ic=kc*8+e][tap][oc=nt*16+n]
__global__ __launch_bounds__(256) void k_prep34s(
    const float* __restrict__ Wpart, const float* __restrict__ Bpart,
    const float* __restrict__ b4,
    ushort_t* __restrict__ Wmf, float* __restrict__ B34)
{
    int i = blockIdx.x * 256 + threadIdx.x;
    if (i < 165888) {
        float s = 0.f;
        #pragma unroll
        for (int c = 0; c < 8; ++c) s += Wpart[c * 165888 + i];
        int oc = i & 63, r = i >> 6;
        int ic = r / 81, uv = r % 81;
        int idx = (uv * 16 + (oc >> 4) * 4 + (ic >> 3)) * 128
                + (oc & 15) * 8 + (ic & 7);
        Wmf[idx] = f2bf(s);
    }
    if (blockIdx.x == 648 && threadIdx.x < 64) {
        int oc = threadIdx.x;
        float s = b4[oc];
        #pragma unroll
        for (int c = 0; c < 8; ++c) s += Bpart[c * 64 + oc];
        B34[oc] = s;
    }
}

// ---------------- kernel B: fused 9x9 conv12 + 4x4 maxpool -> bf16 P1 ----
// P1bf layout: [b][row30][col30][ic32] (ushort bf16)
__global__ __launch_bounds__(256) void k_conv12(
    const float* __restrict__ x, const float* __restrict__ W12,
    const float* __restrict__ B12, ushort_t* __restrict__ P1bf)
{
    __shared__ float sIn[12][128];

    int b  = blockIdx.x / 30;
    int py = blockIdx.x % 30;
    int t  = threadIdx.x;

    const float* xb = x + b * 128 * 128;
    for (int i = t; i < 12 * 32; i += 256) {
        int row = i >> 5, c4 = i & 31;
        ((float4*)sIn[row])[c4] =
            ((const float4*)(xb + (4 * py + row) * 128))[c4];
    }

    int oc = t & 31;
    int pg = t >> 5;
    float w[81];
    #pragma unroll
    for (int e = 0; e < 81; ++e) w[e] = W12[e * 32 + oc];
    float bias = B12[oc];
    __syncthreads();

    for (int j = 0; j < 4; ++j) {
        int px = pg + 8 * j;
        if (px >= 30) break;
        float acc[4][4];
        #pragma unroll
        for (int iy = 0; iy < 4; ++iy)
            #pragma unroll
            for (int ix = 0; ix < 4; ++ix) acc[iy][ix] = 0.f;

        #pragma unroll
        for (int r = 0; r < 12; ++r) {
            const float* rp = sIn[r] + 4 * px;
            float4 A  = ((const float4*)rp)[0];
            float4 Bq = ((const float4*)rp)[1];
            float4 Cq = ((const float4*)rp)[2];
            float win[12] = {A.x, A.y, A.z, A.w, Bq.x, Bq.y, Bq.z, Bq.w,
                             Cq.x, Cq.y, Cq.z, Cq.w};
            #pragma unroll
            for (int iy = 0; iy < 4; ++iy) {
                int ky = r - iy;
                if (ky < 0 || ky > 8) continue;
                #pragma unroll
                for (int ix = 0; ix < 4; ++ix)
                    #pragma unroll
                    for (int kx = 0; kx < 9; ++kx)
                        acc[iy][ix] = fmaf(w[ky * 9 + kx], win[ix + kx],
                                           acc[iy][ix]);
            }
        }
        float m = -INFINITY;
        #pragma unroll
        for (int iy = 0; iy < 4; ++iy)
            #pragma unroll
            for (int ix = 0; ix < 4; ++ix) m = fmaxf(m, acc[iy][ix]);
        P1bf[((b * 30 + py) * 30 + px) * 32 + oc] = f2bf(m + bias);
    }
}

// ---------------- kernel C: conv34 via MFMA (bf16) + fused 4x4 pool -------
// grid = 64 b * 4 nt = 256 blocks; block = 320 = 5 waves (wave = pool-row).
// GEMM: M = pool-cell x within(16), N = 16 oc (nt), K = 81 taps x 32 ic.
// A from LDS (P1bf[b] rows 0..27 staged linearly), B from global (Wmf),
// prefetched one tap ahead. Pool = 3 reg-max + 2 shfl_xor (M-tile = cell).
__global__ __launch_bounds__(320) void k_conv34m(
    const ushort_t* __restrict__ P1bf, const ushort_t* __restrict__ Wmf,
    const float* __restrict__ B34, float* __restrict__ embT)
{
    __shared__ ushort_t sA[28 * 960];   // 53760 B, rows 0..27 of [30][32] bf16

    int b  = blockIdx.x >> 2;
    int nt = blockIdx.x & 3;
    int t  = threadIdx.x;

    // linear stage: first 3360 uint4 of P1bf[b]
    const uint4* gsrc = (const uint4*)(P1bf + b * 28800);
    for (int i = t; i < 3360; i += 320)
        ((uint4*)sA)[i] = gsrc[i];
    __syncthreads();

    int w  = t >> 6;          // wave index = pool row py
    int l  = t & 63;
    int m16 = l & 15;         // within-cell position (iy*4+ix) / D col n
    int kc  = l >> 4;         // ic-chunk
    int iy = m16 >> 2, ix = m16 & 3;

    // A base (ushort index) for cell (w, q=0), tap (0,0)
    int baseU = (w * 4 + iy) * 960 + ix * 32 + kc * 8;

    f32x4 acc0 = {0.f,0.f,0.f,0.f}, acc1 = acc0, acc2 = acc0,
          acc3 = acc0, acc4 = acc0;

    // B pointer for this lane: Wmf[tap*2048 + (nt*4+kc)*128 + m16*8]
    const ushort_t* wp = Wmf + (nt * 4 + kc) * 128 + m16 * 8;

    bf16x8 bcur = *(const bf16x8*)wp;
    int tap = 0;
    for (int ky = 0; ky < 9; ++ky) {
        int rowU = baseU + ky * 960;
        #pragma unroll
        for (int kx = 0; kx < 9; ++kx) {
            bf16x8 bnext = *(const bf16x8*)(wp + (tap + 1) * 2048); // last read harmless (in-ws)
            const ushort_t* ap = sA + rowU + kx * 32;
            bf16x8 a0 = *(const bf16x8*)(ap);
            bf16x8 a1 = *(const bf16x8*)(ap + 128);
            bf16x8 a2 = *(const bf16x8*)(ap + 256);
            bf16x8 a3 = *(const bf16x8*)(ap + 384);
            bf16x8 a4 = *(const bf16x8*)(ap + 512);
            acc0 = __builtin_amdgcn_mfma_f32_16x16x32_bf16(a0, bcur, acc0, 0, 0, 0);
            acc1 = __builtin_amdgcn_mfma_f32_16x16x32_bf16(a1, bcur, acc1, 0, 0, 0);
            acc2 = __builtin_amdgcn_mfma_f32_16x16x32_bf16(a2, bcur, acc2, 0, 0, 0);
            acc3 = __builtin_amdgcn_mfma_f32_16x16x32_bf16(a3, bcur, acc3, 0, 0, 0);
            acc4 = __builtin_amdgcn_mfma_f32_16x16x32_bf16(a4, bcur, acc4, 0, 0, 0);
            bcur = bnext;
            ++tap;
        }
    }

    // epilogue: pool-max each cell tile, write embT
    float bias = B34[nt * 16 + m16];
    #pragma unroll
    for (int q = 0; q < 5; ++q) {
        f32x4 a = (q == 0) ? acc0 : (q == 1) ? acc1 : (q == 2) ? acc2
                : (q == 3) ? acc3 : acc4;
        float mv = fmaxf(fmaxf(a[0], a[1]), fmaxf(a[2], a[3]));
        mv = fmaxf(mv, __shfl_xor(mv, 16, 64));
        mv = fmaxf(mv, __shfl_xor(mv, 32, 64));
        if (l < 16) {
            int oc = nt * 16 + l;
            embT[(oc * 25 + w * 5 + q) * 64 + b] = mv + bias;
        }
    }
}

// ---------------- kernel D1: first FC layer, both heads -------------------
__global__ __launch_bounds__(256) void k_fc1(
    const float* __restrict__ embT,
    const float* __restrict__ w_ed1, const float* __restrict__ b_ed1,
    const float* __restrict__ w_ep1, const float* __restrict__ b_ep1,
    float* __restrict__ hid)
{
    int head = blockIdx.x >> 6;
    int jg   = blockIdx.x & 63;
    int b    = threadIdx.x & 63;
    int jl   = __builtin_amdgcn_readfirstlane(threadIdx.x >> 6);
    int j    = jg * 4 + jl;

    const float* W1 = head ? w_ep1 : w_ed1;
    float s = head ? b_ep1[j] : b_ed1[j];
    #pragma unroll 8
    for (int k = 0; k < 1600; ++k)
        s = fmaf(embT[k * 64 + b], W1[k * 256 + j], s);
    hid[(head * 256 + j) * 64 + b] = fmaxf(s, 0.f);
}

// ---------------- kernel D2: second FC layer (3 cols) + sigmoid product ---
__global__ __launch_bounds__(256) void k_fc2(
    const float* __restrict__ hid,
    const float* __restrict__ w_ed2, const float* __restrict__ b_ed2,
    const float* __restrict__ w_ep2, const float* __restrict__ b_ep2,
    const int* __restrict__ esrc, const int* __restrict__ edst,
    float* __restrict__ out)
{
    __shared__ float sl[192];
    int t = threadIdx.x;
    if (t < 192) {
        int q = __builtin_amdgcn_readfirstlane(t >> 6);
        int b = t & 63;
        int c0 = esrc[0], c1 = edst[0];
        int head = (q > 0) ? 1 : 0;
        float acc = 0.f;
        #pragma unroll 4
        for (int j = 0; j < 256; ++j) {
            float w = (q == 0) ? w_ed2[j * 120]
                    : (q == 1) ? w_ep2[j * 36 + c0]
                               : w_ep2[j * 36 + c1];
            acc = fmaf(hid[(head * 256 + j) * 64 + b], w, acc);
        }
        float bias = (q == 0) ? b_ed2[0] : (q == 1) ? b_ep2[c0] : b_ep2[c1];
        sl[q * 64 + b] = 1.f / (1.f + expf(-(acc + bias)));
    }
    __syncthreads();
    if (t < 64) out[t] = sl[t] * sl[64 + t] * sl[128 + t];
}

// ---------------- launch --------------------------------------------------
extern "C" void kernel_launch(void* const* d_in, const int* in_sizes, int n_in,
                              void* d_out, int out_size, void* d_ws, size_t ws_size,
                              hipStream_t stream)
{
    const float* x     = (const float*)d_in[0];
    const float* w1    = (const float*)d_in[1];
    const float* b1    = (const float*)d_in[2];
    const float* w2    = (const float*)d_in[3];
    const float* b2    = (const float*)d_in[4];
    const float* w3    = (const float*)d_in[5];
    const float* b3    = (const float*)d_in[6];
    const float* w4    = (const float*)d_in[7];
    const float* b4    = (const float*)d_in[8];
    const float* w_ed1 = (const float*)d_in[9];
    const float* b_ed1 = (const float*)d_in[10];
    const float* w_ed2 = (const float*)d_in[11];
    const float* b_ed2 = (const float*)d_in[12];
    const float* w_ep1 = (const float*)d_in[13];
    const float* b_ep1 = (const float*)d_in[14];
    const float* w_ep2 = (const float*)d_in[15];
    const float* b_ep2 = (const float*)d_in[16];
    const int*   esrc  = (const int*)d_in[17];
    const int*   edst  = (const int*)d_in[18];

    float* ws  = (float*)d_ws;
    float* out = (float*)d_out;

    ushort_t* Wmf  = (ushort_t*)(ws + WS_WMF);
    ushort_t* P1bf = (ushort_t*)(ws + WS_P1);

    k_prep12<<<32, 128, 0, stream>>>(w1, b1, w2, b2, ws + WS_W12, ws + WS_B12);
    k_prep34p<<<64, 256, 0, stream>>>(w3, b3, w4, ws + WS_WPART, ws + WS_BPART);
    k_prep34s<<<649, 256, 0, stream>>>(ws + WS_WPART, ws + WS_BPART, b4,
                                       Wmf, ws + WS_B34);
    k_conv12<<<64 * 30, 256, 0, stream>>>(x, ws + WS_W12, ws + WS_B12, P1bf);
    k_conv34m<<<256, 320, 0, stream>>>(P1bf, Wmf, ws + WS_B34, ws + WS_EMBT);
    k_fc1<<<128, 256, 0, stream>>>(ws + WS_EMBT, w_ed1, b_ed1, w_ep1, b_ep1,
                                   ws + WS_HID);
    k_fc2<<<1, 256, 0, stream>>>(ws + WS_HID, w_ed2, b_ed2, w_ep2, b_ep2,
                                 esrc, edst, out);
}

// Round 11
// 128.232 us; speedup vs baseline: 11.8337x; 1.7578x over previous
//
#include <hip/hip_runtime.h>
#include <math.h>

typedef __attribute__((ext_vector_type(8))) short bf16x8;
typedef __attribute__((ext_vector_type(4))) float f32x4;
typedef unsigned short ushort_t;

// ---------------- workspace layout (floats) ----------------
#define WS_W12   0                         // [9*9][32]        = 2592
#define WS_B12   2592                      // 32
#define WS_WMF   2624                      // Wmf bf16: 165888 ushort = 82944 float slots
#define WS_B34   (2624 + 165888)           // 64
#define WS_P1    (WS_B34 + 64)             // P1 bf16: [64][30][30][32] ushort
#define WS_EMB   (WS_P1 + 64*30*30*32)     // [64][1600] = 102400 floats
#define WS_LOG   (WS_EMB + 102400)         // [64][3]
// overlays (lifetimes disjoint):
#define WS_WPART WS_P1                     // [8][165888] floats (before conv12)
#define WS_BPART (WS_P1 + 8*165888)        // [8][64]

__device__ __forceinline__ unsigned short f2bf(float f) {
    unsigned u = __float_as_uint(f);
    u += 0x7FFF + ((u >> 16) & 1);         // RNE
    return (unsigned short)(u >> 16);
}

// ---------------- kernel A1: compose conv1*conv2 -> 9x9, 1->32ch ----------
__global__ __launch_bounds__(128) void k_prep12(
    const float* __restrict__ w1, const float* __restrict__ b1,
    const float* __restrict__ w2, const float* __restrict__ b2,
    float* __restrict__ W12, float* __restrict__ B12)
{
    __shared__ float sW2[800];
    __shared__ float sW1[800];
    int oc = blockIdx.x;
    int t  = threadIdx.x;
    for (int i = t; i < 800; i += 128) {
        sW2[i] = w2[oc * 800 + i];
        sW1[i] = w1[i];
    }
    __syncthreads();
    if (t < 81) {
        int u = t / 9, v = t % 9;
        float acc[4] = {0.f, 0.f, 0.f, 0.f};
        #pragma unroll
        for (int e = 0; e < 25; ++e) {
            int ey = e / 5, ex = e % 5;
            int du = u - ey, dv = v - ex;
            if ((unsigned)du <= 4u && (unsigned)dv <= 4u) {
                int ep = du * 5 + dv;
                for (int mc = 0; mc < 32; ++mc)
                    acc[e & 3] = fmaf(sW2[mc * 25 + e], sW1[mc * 25 + ep],
                                      acc[e & 3]);
            }
        }
        W12[t * 32 + oc] = (acc[0] + acc[1]) + (acc[2] + acc[3]);
    }
    if (t < 32) {
        float ws = 0.f;
        #pragma unroll
        for (int e = 0; e < 25; ++e) ws += sW2[t * 25 + e];
        float p = b1[t] * ws;
        #pragma unroll
        for (int off = 16; off; off >>= 1) p += __shfl_down(p, off, 64);
        if (t == 0) B12[oc] = p + b2[oc];
    }
}

// ---------------- kernel A2a: conv3*conv4 partials (register outer product)
__global__ __launch_bounds__(256) void k_prep34p(
    const float* __restrict__ w3, const float* __restrict__ b3,
    const float* __restrict__ w4,
    float* __restrict__ Wpart, float* __restrict__ Bpart)
{
    __shared__ float sW3c[800];            // [mcl 8][icl 4][e 25]
    int icg = blockIdx.x >> 3;
    int mcc = blockIdx.x & 7;
    int t   = threadIdx.x;
    int oc  = t & 63;
    int icl = t >> 6;                      // wave-uniform
    int ic  = icg * 4 + icl;

    for (int i = t; i < 800; i += 256) {
        int mcl = i / 100, r = i % 100;
        sW3c[i] = w3[(mcc * 8 + mcl) * 800 + icg * 100 + r];
    }
    __syncthreads();

    float acc[81];
    #pragma unroll
    for (int u = 0; u < 81; ++u) acc[u] = 0.f;
    float bacc = 0.f;

    for (int mcl = 0; mcl < 8; ++mcl) {
        int mc = mcc * 8 + mcl;
        float w4r[25];
        #pragma unroll
        for (int e = 0; e < 25; ++e) w4r[e] = w4[oc * 1600 + mc * 25 + e];
        const float* w3r = &sW3c[(mcl * 4 + icl) * 25];
        #pragma unroll
        for (int e2 = 0; e2 < 25; ++e2) {
            int ey = e2 / 5, ex = e2 % 5;
            #pragma unroll
            for (int e1 = 0; e1 < 25; ++e1) {
                int u = (ey + e1 / 5) * 9 + (ex + e1 % 5);   // compile-time
                acc[u] = fmaf(w4r[e2], w3r[e1], acc[u]);
            }
        }
        if (icl == 0) {
            float ws = 0.f;
            #pragma unroll
            for (int e = 0; e < 25; ++e) ws += w4r[e];
            bacc = fmaf(b3[mc], ws, bacc);
        }
    }

    for (int uv = 0; uv < 81; ++uv)
        Wpart[((mcc * 32 + ic) * 81 + uv) * 64 + oc] = acc[uv];
    if (icl == 0) Bpart[mcc * 64 + oc] = bacc;
}

// ---------------- kernel A2b: sum partials -> bf16 MFMA-swizzled weights --
// Wmf[tap][nt4][kc4][n16][e8]: value = W34[ic=kc*8+e][tap][oc=nt*16+n]
__global__ __launch_bounds__(256) void k_prep34s(
    const float* __restrict__ Wpart, const float* __restrict__ Bpart,
    const float* __restrict__ b4,
    ushort_t* __restrict__ Wmf, float* __restrict__ B34)
{
    int i = blockIdx.x * 256 + threadIdx.x;
    if (i < 165888) {
        float s = 0.f;
        #pragma unroll
        for (int c = 0; c < 8; ++c) s += Wpart[c * 165888 + i];
        int oc = i & 63, r = i >> 6;
        int ic = r / 81, uv = r % 81;
        int idx = (uv * 16 + (oc >> 4) * 4 + (ic >> 3)) * 128
                + (oc & 15) * 8 + (ic & 7);
        Wmf[idx] = f2bf(s);
    }
    if (blockIdx.x == 648 && threadIdx.x < 64) {
        int oc = threadIdx.x;
        float s = b4[oc];
        #pragma unroll
        for (int c = 0; c < 8; ++c) s += Bpart[c * 64 + oc];
        B34[oc] = s;
    }
}

// ---------------- kernel B: fused 9x9 conv12 + 4x4 maxpool -> bf16 P1 ----
__global__ __launch_bounds__(256) void k_conv12(
    const float* __restrict__ x, const float* __restrict__ W12,
    const float* __restrict__ B12, ushort_t* __restrict__ P1bf)
{
    __shared__ float sIn[12][128];

    int b  = blockIdx.x / 30;
    int py = blockIdx.x % 30;
    int t  = threadIdx.x;

    const float* xb = x + b * 128 * 128;
    for (int i = t; i < 12 * 32; i += 256) {
        int row = i >> 5, c4 = i & 31;
        ((float4*)sIn[row])[c4] =
            ((const float4*)(xb + (4 * py + row) * 128))[c4];
    }

    int oc = t & 31;
    int pg = t >> 5;
    float w[81];
    #pragma unroll
    for (int e = 0; e < 81; ++e) w[e] = W12[e * 32 + oc];
    float bias = B12[oc];
    __syncthreads();

    for (int j = 0; j < 4; ++j) {
        int px = pg + 8 * j;
        if (px >= 30) break;
        float acc[4][4];
        #pragma unroll
        for (int iy = 0; iy < 4; ++iy)
            #pragma unroll
            for (int ix = 0; ix < 4; ++ix) acc[iy][ix] = 0.f;

        #pragma unroll
        for (int r = 0; r < 12; ++r) {
            const float* rp = sIn[r] + 4 * px;
            float4 A  = ((const float4*)rp)[0];
            float4 Bq = ((const float4*)rp)[1];
            float4 Cq = ((const float4*)rp)[2];
            float win[12] = {A.x, A.y, A.z, A.w, Bq.x, Bq.y, Bq.z, Bq.w,
                             Cq.x, Cq.y, Cq.z, Cq.w};
            #pragma unroll
            for (int iy = 0; iy < 4; ++iy) {
                int ky = r - iy;
                if (ky < 0 || ky > 8) continue;
                #pragma unroll
                for (int ix = 0; ix < 4; ++ix)
                    #pragma unroll
                    for (int kx = 0; kx < 9; ++kx)
                        acc[iy][ix] = fmaf(w[ky * 9 + kx], win[ix + kx],
                                           acc[iy][ix]);
            }
        }
        float m = -INFINITY;
        #pragma unroll
        for (int iy = 0; iy < 4; ++iy)
            #pragma unroll
            for (int ix = 0; ix < 4; ++ix) m = fmaxf(m, acc[iy][ix]);
        P1bf[((b * 30 + py) * 30 + px) * 32 + oc] = f2bf(m + bias);
    }
}

// ---------------- kernel C: conv34 via MFMA (bf16) + fused 4x4 pool -------
// writes emb[b][oc*25 + py*5 + px] (row-major per batch)
__global__ __launch_bounds__(320) void k_conv34m(
    const ushort_t* __restrict__ P1bf, const ushort_t* __restrict__ Wmf,
    const float* __restrict__ B34, float* __restrict__ emb)
{
    __shared__ ushort_t sA[28 * 960];   // 53760 B

    int b  = blockIdx.x >> 2;
    int nt = blockIdx.x & 3;
    int t  = threadIdx.x;

    const uint4* gsrc = (const uint4*)(P1bf + b * 28800);
    for (int i = t; i < 3360; i += 320)
        ((uint4*)sA)[i] = gsrc[i];
    __syncthreads();

    int w  = t >> 6;          // wave index = pool row py
    int l  = t & 63;
    int m16 = l & 15;
    int kc  = l >> 4;
    int iy = m16 >> 2, ix = m16 & 3;

    int baseU = (w * 4 + iy) * 960 + ix * 32 + kc * 8;

    f32x4 acc0 = {0.f,0.f,0.f,0.f}, acc1 = acc0, acc2 = acc0,
          acc3 = acc0, acc4 = acc0;

    const ushort_t* wp = Wmf + (nt * 4 + kc) * 128 + m16 * 8;

    bf16x8 bcur = *(const bf16x8*)wp;
    int tap = 0;
    for (int ky = 0; ky < 9; ++ky) {
        int rowU = baseU + ky * 960;
        #pragma unroll
        for (int kx = 0; kx < 9; ++kx) {
            bf16x8 bnext = *(const bf16x8*)(wp + (tap + 1) * 2048);
            const ushort_t* ap = sA + rowU + kx * 32;
            bf16x8 a0 = *(const bf16x8*)(ap);
            bf16x8 a1 = *(const bf16x8*)(ap + 128);
            bf16x8 a2 = *(const bf16x8*)(ap + 256);
            bf16x8 a3 = *(const bf16x8*)(ap + 384);
            bf16x8 a4 = *(const bf16x8*)(ap + 512);
            acc0 = __builtin_amdgcn_mfma_f32_16x16x32_bf16(a0, bcur, acc0, 0, 0, 0);
            acc1 = __builtin_amdgcn_mfma_f32_16x16x32_bf16(a1, bcur, acc1, 0, 0, 0);
            acc2 = __builtin_amdgcn_mfma_f32_16x16x32_bf16(a2, bcur, acc2, 0, 0, 0);
            acc3 = __builtin_amdgcn_mfma_f32_16x16x32_bf16(a3, bcur, acc3, 0, 0, 0);
            acc4 = __builtin_amdgcn_mfma_f32_16x16x32_bf16(a4, bcur, acc4, 0, 0, 0);
            bcur = bnext;
            ++tap;
        }
    }

    float bias = B34[nt * 16 + m16];
    #pragma unroll
    for (int q = 0; q < 5; ++q) {
        f32x4 a = (q == 0) ? acc0 : (q == 1) ? acc1 : (q == 2) ? acc2
                : (q == 3) ? acc3 : acc4;
        float mv = fmaxf(fmaxf(a[0], a[1]), fmaxf(a[2], a[3]));
        mv = fmaxf(mv, __shfl_xor(mv, 16, 64));
        mv = fmaxf(mv, __shfl_xor(mv, 32, 64));
        if (l < 16) {
            int oc = nt * 16 + l;
            emb[b * 1600 + oc * 25 + w * 5 + q] = mv + bias;
        }
    }
}

// ---------------- kernel D: FC heads fused (fc1 + needed fc2 cols) --------
// grid = 128 (head*64 + b); block = 512 = 2 K-halves x 256 j.
// emb[b] in LDS; W1 reads coalesced over j lanes; K-halves merged via LDS.
__global__ __launch_bounds__(512) void k_fc(
    const float* __restrict__ emb,
    const float* __restrict__ w_ed1, const float* __restrict__ b_ed1,
    const float* __restrict__ w_ed2, const float* __restrict__ b_ed2,
    const float* __restrict__ w_ep1, const float* __restrict__ b_ep1,
    const float* __restrict__ w_ep2, const float* __restrict__ b_ep2,
    const int* __restrict__ esrc, const int* __restrict__ edst,
    float* __restrict__ logits)
{
    __shared__ float se[1600];
    __shared__ float sh[2][256];
    __shared__ float sred[2][4];

    int head = blockIdx.x >> 6;
    int b    = blockIdx.x & 63;
    int t    = threadIdx.x;
    int j    = t & 255;
    int kh   = t >> 8;                    // 0/1, wave-uniform

    {
        const float4* src = (const float4*)(emb + b * 1600);
        for (int i = t; i < 400; i += 512) ((float4*)se)[i] = src[i];
    }
    __syncthreads();

    const float* W1 = head ? w_ep1 : w_ed1;
    float a0 = 0.f, a1 = 0.f, a2 = 0.f, a3 = 0.f;
    int k0 = kh * 800;
    #pragma unroll 8
    for (int k = k0; k < k0 + 800; k += 4) {
        a0 = fmaf(se[k + 0], W1[(k + 0) * 256 + j], a0);
        a1 = fmaf(se[k + 1], W1[(k + 1) * 256 + j], a1);
        a2 = fmaf(se[k + 2], W1[(k + 2) * 256 + j], a2);
        a3 = fmaf(se[k + 3], W1[(k + 3) * 256 + j], a3);
    }
    sh[kh][j] = (a0 + a1) + (a2 + a3);
    __syncthreads();

    int c0 = esrc[0], c1 = edst[0];
    if (t < 256) {
        float bias1 = head ? b_ep1[j] : b_ed1[j];
        float h = fmaxf(bias1 + sh[0][j] + sh[1][j], 0.f);
        if (head == 0) {
            float p = h * w_ed2[j * 120];
            #pragma unroll
            for (int off = 32; off; off >>= 1) p += __shfl_down(p, off, 64);
            if ((t & 63) == 0) sred[0][t >> 6] = p;
        } else {
            float p0 = h * w_ep2[j * 36 + c0];
            float p1 = h * w_ep2[j * 36 + c1];
            #pragma unroll
            for (int off = 32; off; off >>= 1) {
                p0 += __shfl_down(p0, off, 64);
                p1 += __shfl_down(p1, off, 64);
            }
            if ((t & 63) == 0) {
                sred[0][t >> 6] = p0;
                sred[1][t >> 6] = p1;
            }
        }
    }
    __syncthreads();
    if (t == 0) {
        float s0 = (sred[0][0] + sred[0][1]) + (sred[0][2] + sred[0][3]);
        if (head == 0) {
            logits[b * 3 + 0] = s0 + b_ed2[0];
        } else {
            float s1 = (sred[1][0] + sred[1][1]) + (sred[1][2] + sred[1][3]);
            logits[b * 3 + 1] = s0 + b_ep2[c0];
            logits[b * 3 + 2] = s1 + b_ep2[c1];
        }
    }
}

// ---------------- kernel E: sigmoid products -> out ----------------------
__global__ __launch_bounds__(64) void k_final(
    const float* __restrict__ logits, float* __restrict__ out)
{
    int b = threadIdx.x;
    if (b < 64) {
        float e  = logits[b * 3 + 0];
        float p0 = logits[b * 3 + 1];
        float p1 = logits[b * 3 + 2];
        out[b] = (1.f / (1.f + expf(-e))) *
                 (1.f / (1.f + expf(-p0))) *
                 (1.f / (1.f + expf(-p1)));
    }
}

// ---------------- launch --------------------------------------------------
extern "C" void kernel_launch(void* const* d_in, const int* in_sizes, int n_in,
                              void* d_out, int out_size, void* d_ws, size_t ws_size,
                              hipStream_t stream)
{
    const float* x     = (const float*)d_in[0];
    const float* w1    = (const float*)d_in[1];
    const float* b1    = (const float*)d_in[2];
    const float* w2    = (const float*)d_in[3];
    const float* b2    = (const float*)d_in[4];
    const float* w3    = (const float*)d_in[5];
    const float* b3    = (const float*)d_in[6];
    const float* w4    = (const float*)d_in[7];
    const float* b4    = (const float*)d_in[8];
    const float* w_ed1 = (const float*)d_in[9];
    const float* b_ed1 = (const float*)d_in[10];
    const float* w_ed2 = (const float*)d_in[11];
    const float* b_ed2 = (const float*)d_in[12];
    const float* w_ep1 = (const float*)d_in[13];
    const float* b_ep1 = (const float*)d_in[14];
    const float* w_ep2 = (const float*)d_in[15];
    const float* b_ep2 = (const float*)d_in[16];
    const int*   esrc  = (const int*)d_in[17];
    const int*   edst  = (const int*)d_in[18];

    float* ws  = (float*)d_ws;
    float* out = (float*)d_out;

    ushort_t* Wmf  = (ushort_t*)(ws + WS_WMF);
    ushort_t* P1bf = (ushort_t*)(ws + WS_P1);

    k_prep12<<<32, 128, 0, stream>>>(w1, b1, w2, b2, ws + WS_W12, ws + WS_B12);
    k_prep34p<<<64, 256, 0, stream>>>(w3, b3, w4, ws + WS_WPART, ws + WS_BPART);
    k_prep34s<<<649, 256, 0, stream>>>(ws + WS_WPART, ws + WS_BPART, b4,
                                       Wmf, ws + WS_B34);
    k_conv12<<<64 * 30, 256, 0, stream>>>(x, ws + WS_W12, ws + WS_B12, P1bf);
    k_conv34m<<<256, 320, 0, stream>>>(P1bf, Wmf, ws + WS_B34, ws + WS_EMB);
    k_fc<<<128, 512, 0, stream>>>(ws + WS_EMB, w_ed1, b_ed1, w_ed2, b_ed2,
                                  w_ep1, b_ep1, w_ep2, b_ep2, esrc, edst,
                                  ws + WS_LOG);
    k_final<<<1, 64, 0, stream>>>(ws + WS_LOG, out);
}

// Round 12
// 88.691 us; speedup vs baseline: 17.1095x; 1.4458x over previous
//
#include <hip/hip_runtime.h>
#include <math.h>

typedef __attribute__((ext_vector_type(8))) short bf16x8;
typedef __attribute__((ext_vector_type(4))) float f32x4;
typedef unsigned short ushort_t;

// ---------------- workspace layout (floats) ----------------
#define WS_W12   0                         // [9*9][32] fp32   = 2592
#define WS_B12   2592                      // 32
#define WS_WMF   2624                      // conv34 Wmf bf16 (165888 ushort; slack)
#define WS_B34   (2624 + 165888)           // 64
#define WS_WMF12 (WS_B34 + 64)             // conv12 Wmf bf16: 5120 ushort = 2560 fl
#define WS_P1    (WS_WMF12 + 2560)         // P1 bf16: [64][30][30][32] ushort
#define WS_EMB   (WS_P1 + 64*30*30*32)     // [64][1600] floats (P1 slot 2x slack)
#define WS_LOG   (WS_EMB + 102400)         // [64][3]
// overlays (lifetimes disjoint):
#define WS_WPART WS_P1                     // [8][165888] floats (before conv12m)
#define WS_BPART (WS_P1 + 8*165888)        // [8][64]

#define PLST 1880                          // LDS shift-plane stride (elems)

__device__ __forceinline__ unsigned short f2bf(float f) {
    unsigned u = __float_as_uint(f);
    u += 0x7FFF + ((u >> 16) & 1);         // RNE
    return (unsigned short)(u >> 16);
}

// ---------------- kernel A1: compose conv1*conv2 -> 9x9, 1->32ch ----------
__global__ __launch_bounds__(128) void k_prep12(
    const float* __restrict__ w1, const float* __restrict__ b1,
    const float* __restrict__ w2, const float* __restrict__ b2,
    float* __restrict__ W12, float* __restrict__ B12)
{
    __shared__ float sW2[800];
    __shared__ float sW1[800];
    int oc = blockIdx.x;
    int t  = threadIdx.x;
    for (int i = t; i < 800; i += 128) {
        sW2[i] = w2[oc * 800 + i];
        sW1[i] = w1[i];
    }
    __syncthreads();
    if (t < 81) {
        int u = t / 9, v = t % 9;
        float acc[4] = {0.f, 0.f, 0.f, 0.f};
        #pragma unroll
        for (int e = 0; e < 25; ++e) {
            int ey = e / 5, ex = e % 5;
            int du = u - ey, dv = v - ex;
            if ((unsigned)du <= 4u && (unsigned)dv <= 4u) {
                int ep = du * 5 + dv;
                for (int mc = 0; mc < 32; ++mc)
                    acc[e & 3] = fmaf(sW2[mc * 25 + e], sW1[mc * 25 + ep],
                                      acc[e & 3]);
            }
        }
        W12[t * 32 + oc] = (acc[0] + acc[1]) + (acc[2] + acc[3]);
    }
    if (t < 32) {
        float ws = 0.f;
        #pragma unroll
        for (int e = 0; e < 25; ++e) ws += sW2[t * 25 + e];
        float p = b1[t] * ws;
        #pragma unroll
        for (int off = 16; off; off >>= 1) p += __shfl_down(p, off, 64);
        if (t == 0) B12[oc] = p + b2[oc];
    }
}

// ---------------- kernel A2a: conv3*conv4 partials (register outer product)
__global__ __launch_bounds__(256) void k_prep34p(
    const float* __restrict__ w3, const float* __restrict__ b3,
    const float* __restrict__ w4,
    float* __restrict__ Wpart, float* __restrict__ Bpart)
{
    __shared__ float sW3c[800];            // [mcl 8][icl 4][e 25]
    int icg = blockIdx.x >> 3;
    int mcc = blockIdx.x & 7;
    int t   = threadIdx.x;
    int oc  = t & 63;
    int icl = t >> 6;                      // wave-uniform
    int ic  = icg * 4 + icl;

    for (int i = t; i < 800; i += 256) {
        int mcl = i / 100, r = i % 100;
        sW3c[i] = w3[(mcc * 8 + mcl) * 800 + icg * 100 + r];
    }
    __syncthreads();

    float acc[81];
    #pragma unroll
    for (int u = 0; u < 81; ++u) acc[u] = 0.f;
    float bacc = 0.f;

    for (int mcl = 0; mcl < 8; ++mcl) {
        int mc = mcc * 8 + mcl;
        float w4r[25];
        #pragma unroll
        for (int e = 0; e < 25; ++e) w4r[e] = w4[oc * 1600 + mc * 25 + e];
        const float* w3r = &sW3c[(mcl * 4 + icl) * 25];
        #pragma unroll
        for (int e2 = 0; e2 < 25; ++e2) {
            int ey = e2 / 5, ex = e2 % 5;
            #pragma unroll
            for (int e1 = 0; e1 < 25; ++e1) {
                int u = (ey + e1 / 5) * 9 + (ex + e1 % 5);   // compile-time
                acc[u] = fmaf(w4r[e2], w3r[e1], acc[u]);
            }
        }
        if (icl == 0) {
            float ws = 0.f;
            #pragma unroll
            for (int e = 0; e < 25; ++e) ws += w4r[e];
            bacc = fmaf(b3[mc], ws, bacc);
        }
    }

    for (int uv = 0; uv < 81; ++uv)
        Wpart[((mcc * 32 + ic) * 81 + uv) * 64 + oc] = acc[uv];
    if (icl == 0) Bpart[mcc * 64 + oc] = bacc;
}

// ---------------- kernel A2b: sum partials -> bf16 weights (both convs) ---
// blocks 0..647: conv34 Wmf; 648: B34 bias; 649..668: conv12 Wmf12 pack.
__global__ __launch_bounds__(256) void k_prep34s(
    const float* __restrict__ Wpart, const float* __restrict__ Bpart,
    const float* __restrict__ b4, const float* __restrict__ W12,
    ushort_t* __restrict__ Wmf, float* __restrict__ B34,
    ushort_t* __restrict__ Wmf12)
{
    int bid = blockIdx.x;
    int t   = threadIdx.x;
    int i   = bid * 256 + t;
    if (i < 165888) {
        float s = 0.f;
        #pragma unroll
        for (int c = 0; c < 8; ++c) s += Wpart[c * 165888 + i];
        int oc = i & 63, r = i >> 6;
        int ic = r / 81, uv = r % 81;
        int idx = (uv * 16 + (oc >> 4) * 4 + (ic >> 3)) * 128
                + (oc & 15) * 8 + (ic & 7);
        Wmf[idx] = f2bf(s);
    }
    if (bid == 648 && t < 64) {
        int oc = t;
        float s = b4[oc];
        #pragma unroll
        for (int c = 0; c < 8; ++c) s += Bpart[c * 64 + oc];
        B34[oc] = s;
    }
    if (bid >= 649) {
        int i2 = (bid - 649) * 256 + t;        // 0..5119
        int e   = i2 & 7;
        int n   = (i2 >> 3) & 15;
        int kc  = (i2 >> 7) & 3;
        int so  = i2 >> 9;                      // s*2 + och, 0..9
        int s   = so >> 1, och = so & 1;
        int ky  = 2 * s + (kc >> 1);
        int kx  = 8 * (kc & 1) + e;
        float v = (ky <= 8 && kx <= 8) ? W12[(ky * 9 + kx) * 32 + och * 16 + n]
                                       : 0.f;
        Wmf12[i2] = f2bf(v);
    }
}

// ---------------- kernel B: conv12 via MFMA + fused 4x4 pool -> bf16 P1 ---
// grid = (b,py) = 1920; block = 256 = 4 waves, wave w handles x-tiles 2w,2w+1.
// LDS: 8 shift-replicated bf16 planes of 13 input rows (plane p holds
// x[r][q+p]) so every lane's A-fragment is an aligned ds_read_b128.
// K = 81 taps packed as 5 x K32 (ky-pair x kx-octet; pads are zero weights).
__global__ __launch_bounds__(256) void k_conv12m(
    const float* __restrict__ x, const ushort_t* __restrict__ Wmf12,
    const float* __restrict__ B12, ushort_t* __restrict__ P1bf)
{
    __shared__ ushort_t sX[8 * PLST];      // 30080 B

    int b  = blockIdx.x / 30;
    int py = blockIdx.x % 30;
    int t  = threadIdx.x;

    // ---- staging: 13 rows x 17 qgroups, each -> 8 shifted plane writes ----
    if (t < 221) {
        int rowL = t / 17, qg = t % 17;
        int absrow = 4 * py + rowL;
        if (absrow > 127) absrow = 127;     // row only feeds zero-weight taps
        const float* xr = x + (b * 128 + absrow) * 128;
        int c0 = qg * 8;
        float fs[16];
        #pragma unroll
        for (int q4 = 0; q4 < 4; ++q4) {
            int c = c0 + 4 * q4;
            float4 f;
            if (c <= 124) f = *(const float4*)(xr + c);
            else { f.x = 0.f; f.y = 0.f; f.z = 0.f; f.w = 0.f; }
            fs[4 * q4 + 0] = f.x; fs[4 * q4 + 1] = f.y;
            fs[4 * q4 + 2] = f.z; fs[4 * q4 + 3] = f.w;
        }
        unsigned d[8];
        #pragma unroll
        for (int j = 0; j < 8; ++j)
            d[j] = (unsigned)f2bf(fs[2 * j]) |
                   ((unsigned)f2bf(fs[2 * j + 1]) << 16);
        int eoff = rowL * 144 + c0;
        #pragma unroll
        for (int p = 0; p < 8; ++p) {
            uint4 wv;
            int k = p >> 1;
            if ((p & 1) == 0) {
                wv.x = d[k]; wv.y = d[k + 1]; wv.z = d[k + 2]; wv.w = d[k + 3];
            } else {
                wv.x = (d[k] >> 16)     | (d[k + 1] << 16);
                wv.y = (d[k + 1] >> 16) | (d[k + 2] << 16);
                wv.z = (d[k + 2] >> 16) | (d[k + 3] << 16);
                wv.w = (d[k + 3] >> 16) | (d[k + 4] << 16);
            }
            *(uint4*)(sX + p * PLST + eoff) = wv;
        }
    }

    // ---- B-fragments + biases into registers (reused all block) ----
    int l   = t & 63;
    int wv_ = t >> 6;                       // wave = x-tile pair
    int m16 = l & 15;
    int kc  = l >> 4;

    bf16x8 Bf[5][2];
    {
        const ushort_t* wb = Wmf12 + kc * 128 + m16 * 8;
        #pragma unroll
        for (int s = 0; s < 5; ++s)
            #pragma unroll
            for (int och = 0; och < 2; ++och)
                Bf[s][och] = *(const bf16x8*)(wb + (s * 2 + och) * 512);
    }
    float bias0 = B12[m16];
    float bias1 = B12[16 + m16];
    __syncthreads();

    int baseC = (m16 & 7) * PLST + (kc >> 1) * 144
              + 8 * (m16 >> 3) + 8 * (kc & 1);

    #pragma unroll
    for (int xi = 0; xi < 2; ++xi) {
        int xt = wv_ * 2 + xi;
        const ushort_t* ap = sX + baseC + xt * 16;
        float pm0 = -INFINITY, pm1 = -INFINITY;
        #pragma unroll
        for (int y = 0; y < 4; ++y) {
            f32x4 a0 = {0.f, 0.f, 0.f, 0.f}, a1 = a0;
            #pragma unroll
            for (int s = 0; s < 5; ++s) {
                bf16x8 av = *(const bf16x8*)(ap + (y + 2 * s) * 144);
                a0 = __builtin_amdgcn_mfma_f32_16x16x32_bf16(av, Bf[s][0], a0, 0, 0, 0);
                a1 = __builtin_amdgcn_mfma_f32_16x16x32_bf16(av, Bf[s][1], a1, 0, 0, 0);
            }
            pm0 = fmaxf(pm0, fmaxf(fmaxf(a0[0], a0[1]), fmaxf(a0[2], a0[3])));
            pm1 = fmaxf(pm1, fmaxf(fmaxf(a1[0], a1[1]), fmaxf(a1[2], a1[3])));
        }
        int px = xt * 4 + (l >> 4);
        if (px < 30) {
            int ob = ((b * 30 + py) * 30 + px) * 32 + m16;
            P1bf[ob]      = f2bf(pm0 + bias0);
            P1bf[ob + 16] = f2bf(pm1 + bias1);
        }
    }
}

// ---------------- kernel C: conv34 via MFMA (bf16) + fused 4x4 pool -------
__global__ __launch_bounds__(320) void k_conv34m(
    const ushort_t* __restrict__ P1bf, const ushort_t* __restrict__ Wmf,
    const float* __restrict__ B34, float* __restrict__ emb)
{
    __shared__ ushort_t sA[28 * 960];   // 53760 B

    int b  = blockIdx.x >> 2;
    int nt = blockIdx.x & 3;
    int t  = threadIdx.x;

    const uint4* gsrc = (const uint4*)(P1bf + b * 28800);
    for (int i = t; i < 3360; i += 320)
        ((uint4*)sA)[i] = gsrc[i];
    __syncthreads();

    int w  = t >> 6;          // wave index = pool row py
    int l  = t & 63;
    int m16 = l & 15;
    int kc  = l >> 4;
    int iy = m16 >> 2, ix = m16 & 3;

    int baseU = (w * 4 + iy) * 960 + ix * 32 + kc * 8;

    f32x4 acc0 = {0.f,0.f,0.f,0.f}, acc1 = acc0, acc2 = acc0,
          acc3 = acc0, acc4 = acc0;

    const ushort_t* wp = Wmf + (nt * 4 + kc) * 128 + m16 * 8;

    bf16x8 bcur = *(const bf16x8*)wp;
    int tap = 0;
    for (int ky = 0; ky < 9; ++ky) {
        int rowU = baseU + ky * 960;
        #pragma unroll
        for (int kx = 0; kx < 9; ++kx) {
            bf16x8 bnext = *(const bf16x8*)(wp + (tap + 1) * 2048);
            const ushort_t* ap = sA + rowU + kx * 32;
            bf16x8 a0 = *(const bf16x8*)(ap);
            bf16x8 a1 = *(const bf16x8*)(ap + 128);
            bf16x8 a2 = *(const bf16x8*)(ap + 256);
            bf16x8 a3 = *(const bf16x8*)(ap + 384);
            bf16x8 a4 = *(const bf16x8*)(ap + 512);
            acc0 = __builtin_amdgcn_mfma_f32_16x16x32_bf16(a0, bcur, acc0, 0, 0, 0);
            acc1 = __builtin_amdgcn_mfma_f32_16x16x32_bf16(a1, bcur, acc1, 0, 0, 0);
            acc2 = __builtin_amdgcn_mfma_f32_16x16x32_bf16(a2, bcur, acc2, 0, 0, 0);
            acc3 = __builtin_amdgcn_mfma_f32_16x16x32_bf16(a3, bcur, acc3, 0, 0, 0);
            acc4 = __builtin_amdgcn_mfma_f32_16x16x32_bf16(a4, bcur, acc4, 0, 0, 0);
            bcur = bnext;
            ++tap;
        }
    }

    float bias = B34[nt * 16 + m16];
    #pragma unroll
    for (int q = 0; q < 5; ++q) {
        f32x4 a = (q == 0) ? acc0 : (q == 1) ? acc1 : (q == 2) ? acc2
                : (q == 3) ? acc3 : acc4;
        float mv = fmaxf(fmaxf(a[0], a[1]), fmaxf(a[2], a[3]));
        mv = fmaxf(mv, __shfl_xor(mv, 16, 64));
        mv = fmaxf(mv, __shfl_xor(mv, 32, 64));
        if (l < 16) {
            int oc = nt * 16 + l;
            emb[b * 1600 + oc * 25 + w * 5 + q] = mv + bias;
        }
    }
}

// ---------------- kernel D: FC heads fused (fc1 + needed fc2 cols) --------
__global__ __launch_bounds__(512) void k_fc(
    const float* __restrict__ emb,
    const float* __restrict__ w_ed1, const float* __restrict__ b_ed1,
    const float* __restrict__ w_ed2, const float* __restrict__ b_ed2,
    const float* __restrict__ w_ep1, const float* __restrict__ b_ep1,
    const float* __restrict__ w_ep2, const float* __restrict__ b_ep2,
    const int* __restrict__ esrc, const int* __restrict__ edst,
    float* __restrict__ logits)
{
    __shared__ float se[1600];
    __shared__ float sh[2][256];
    __shared__ float sred[2][4];

    int head = blockIdx.x >> 6;
    int b    = blockIdx.x & 63;
    int t    = threadIdx.x;
    int j    = t & 255;
    int kh   = t >> 8;                    // 0/1, wave-uniform

    {
        const float4* src = (const float4*)(emb + b * 1600);
        for (int i = t; i < 400; i += 512) ((float4*)se)[i] = src[i];
    }
    __syncthreads();

    const float* W1 = head ? w_ep1 : w_ed1;
    float a0 = 0.f, a1 = 0.f, a2 = 0.f, a3 = 0.f;
    int k0 = kh * 800;
    #pragma unroll 8
    for (int k = k0; k < k0 + 800; k += 4) {
        a0 = fmaf(se[k + 0], W1[(k + 0) * 256 + j], a0);
        a1 = fmaf(se[k + 1], W1[(k + 1) * 256 + j], a1);
        a2 = fmaf(se[k + 2], W1[(k + 2) * 256 + j], a2);
        a3 = fmaf(se[k + 3], W1[(k + 3) * 256 + j], a3);
    }
    sh[kh][j] = (a0 + a1) + (a2 + a3);
    __syncthreads();

    int c0 = esrc[0], c1 = edst[0];
    if (t < 256) {
        float bias1 = head ? b_ep1[j] : b_ed1[j];
        float h = fmaxf(bias1 + sh[0][j] + sh[1][j], 0.f);
        if (head == 0) {
            float p = h * w_ed2[j * 120];
            #pragma unroll
            for (int off = 32; off; off >>= 1) p += __shfl_down(p, off, 64);
            if ((t & 63) == 0) sred[0][t >> 6] = p;
        } else {
            float p0 = h * w_ep2[j * 36 + c0];
            float p1 = h * w_ep2[j * 36 + c1];
            #pragma unroll
            for (int off = 32; off; off >>= 1) {
                p0 += __shfl_down(p0, off, 64);
                p1 += __shfl_down(p1, off, 64);
            }
            if ((t & 63) == 0) {
                sred[0][t >> 6] = p0;
                sred[1][t >> 6] = p1;
            }
        }
    }
    __syncthreads();
    if (t == 0) {
        float s0 = (sred[0][0] + sred[0][1]) + (sred[0][2] + sred[0][3]);
        if (head == 0) {
            logits[b * 3 + 0] = s0 + b_ed2[0];
        } else {
            float s1 = (sred[1][0] + sred[1][1]) + (sred[1][2] + sred[1][3]);
            logits[b * 3 + 1] = s0 + b_ep2[c0];
            logits[b * 3 + 2] = s1 + b_ep2[c1];
        }
    }
}

// ---------------- kernel E: sigmoid products -> out ----------------------
__global__ __launch_bounds__(64) void k_final(
    const float* __restrict__ logits, float* __restrict__ out)
{
    int b = threadIdx.x;
    if (b < 64) {
        float e  = logits[b * 3 + 0];
        float p0 = logits[b * 3 + 1];
        float p1 = logits[b * 3 + 2];
        out[b] = (1.f / (1.f + expf(-e))) *
                 (1.f / (1.f + expf(-p0))) *
                 (1.f / (1.f + expf(-p1)));
    }
}

// ---------------- launch --------------------------------------------------
extern "C" void kernel_launch(void* const* d_in, const int* in_sizes, int n_in,
                              void* d_out, int out_size, void* d_ws, size_t ws_size,
                              hipStream_t stream)
{
    const float* x     = (const float*)d_in[0];
    const float* w1    = (const float*)d_in[1];
    const float* b1    = (const float*)d_in[2];
    const float* w2    = (const float*)d_in[3];
    const float* b2    = (const float*)d_in[4];
    const float* w3    = (const float*)d_in[5];
    const float* b3    = (const float*)d_in[6];
    const float* w4    = (const float*)d_in[7];
    const float* b4    = (const float*)d_in[8];
    const float* w_ed1 = (const float*)d_in[9];
    const float* b_ed1 = (const float*)d_in[10];
    const float* w_ed2 = (const float*)d_in[11];
    const float* b_ed2 = (const float*)d_in[12];
    const float* w_ep1 = (const float*)d_in[13];
    const float* b_ep1 = (const float*)d_in[14];
    const float* w_ep2 = (const float*)d_in[15];
    const float* b_ep2 = (const float*)d_in[16];
    const int*   esrc  = (const int*)d_in[17];
    const int*   edst  = (const int*)d_in[18];

    float* ws  = (float*)d_ws;
    float* out = (float*)d_out;

    ushort_t* Wmf   = (ushort_t*)(ws + WS_WMF);
    ushort_t* Wmf12 = (ushort_t*)(ws + WS_WMF12);
    ushort_t* P1bf  = (ushort_t*)(ws + WS_P1);

    k_prep12<<<32, 128, 0, stream>>>(w1, b1, w2, b2, ws + WS_W12, ws + WS_B12);
    k_prep34p<<<64, 256, 0, stream>>>(w3, b3, w4, ws + WS_WPART, ws + WS_BPART);
    k_prep34s<<<669, 256, 0, stream>>>(ws + WS_WPART, ws + WS_BPART, b4,
                                       ws + WS_W12, Wmf, ws + WS_B34, Wmf12);
    k_conv12m<<<64 * 30, 256, 0, stream>>>(x, Wmf12, ws + WS_B12, P1bf);
    k_conv34m<<<256, 320, 0, stream>>>(P1bf, Wmf, ws + WS_B34, ws + WS_EMB);
    k_fc<<<128, 512, 0, stream>>>(ws + WS_EMB, w_ed1, b_ed1, w_ed2, b_ed2,
                                  w_ep1, b_ep1, w_ep2, b_ep2, esrc, edst,
                                  ws + WS_LOG);
    k_final<<<1, 64, 0, stream>>>(ws + WS_LOG, out);
}